// Round 2
// baseline (793.867 us; speedup 1.0000x reference)
//
#include <hip/hip_runtime.h>
#include <hip/hip_bf16.h>
#include <math.h>

#define VN 4096
#define DIM 128
#define KS 3
#define NH 4
#define HD 32
#define NVIS 8192
#define MAXC 32
#define KTOT (KS*VN)   // 12288

typedef unsigned short u16;
typedef __attribute__((ext_vector_type(8))) short short8;   // 8 bf16 (4 VGPRs)
typedef __attribute__((ext_vector_type(4))) float f32x4;
typedef __attribute__((ext_vector_type(4))) float f4v;      // for nontemporal loads

__device__ __forceinline__ u16 f2b(float f){
  union { float f; unsigned u; } c; c.f = f;
  unsigned u = c.u;
  return (u16)((u + 0x7fffu + ((u >> 16) & 1u)) >> 16);   // RTNE
}
__device__ __forceinline__ float b2f(u16 x){
  union { float f; unsigned u; } c; c.u = ((unsigned)x) << 16; return c.f;
}
// packed f32x2 -> bf16x2 (RTNE), dst.lo = lo, dst.hi = hi
__device__ __forceinline__ unsigned cvt2(float lo, float hi){
  unsigned r;
  asm("v_cvt_pk_bf16_f32 %0, %1, %2" : "=v"(r) : "v"(lo), "v"(hi));
  return r;
}
#define MFMA16(a,b,c) __builtin_amdgcn_mfma_f32_16x16x32_bf16((a),(b),(c),0,0,0)

// ---------------- logmap0 (f32 in, bf16 out):  Z0 = artanh(||x||)/||x|| * x ----------------
__global__ __launch_bounds__(256) void k_logmap(const float* __restrict__ xh, u16* __restrict__ z0){
  __shared__ float xs[64][132];
  __shared__ float part[4][64];
  __shared__ float sscale[64];
  int t = threadIdx.x;
  int v0 = blockIdx.x * 64;
  #pragma unroll
  for(int i=0;i<8;i++){
    int id = t + 256*i; int e = id*4; int r = e>>7; int c = e&127;
    float4 u = *(const float4*)&xh[(size_t)(v0+r)*DIM + c];
    xs[r][c+0]=u.x; xs[r][c+1]=u.y; xs[r][c+2]=u.z; xs[r][c+3]=u.w;
  }
  __syncthreads();
  int r = t & 63, q = t >> 6;
  float p = 0.f;
  #pragma unroll
  for(int c=0;c<32;c++){ float x = xs[r][q*32+c]; p += x*x; }
  part[q][r] = p;
  __syncthreads();
  if(t < 64){
    float ss = part[0][t]+part[1][t]+part[2][t]+part[3][t];
    float n = sqrtf(ss);
    float nc = fminf(fmaxf(n, 1e-7f), 1.0f - 1e-5f);
    sscale[t] = atanhf(nc) / fmaxf(n, 1e-7f);
  }
  __syncthreads();
  #pragma unroll
  for(int i=0;i<8;i++){
    int id = t + 256*i; int e = id*4; int rr = e>>7; int cc = e&127;
    float s = sscale[rr];
    uint2 o = { cvt2(xs[rr][cc+0]*s, xs[rr][cc+1]*s),
                cvt2(xs[rr][cc+2]*s, xs[rr][cc+3]*s) };
    *(uint2*)&z0[(size_t)(v0+rr)*DIM + cc] = o;
  }
}

// ---------------- shared 128x128-tile GEMM core, K=128 (BK=64 x 2), pipelined ----------------
template<bool AF32, bool BF32>
__device__ __forceinline__ void gemm_k128_t(const void* __restrict__ Agv, int lda,
                                            const void* __restrict__ Bgv, int ldb,
                                            u16 (*As)[128*72], u16 (*Bs)[128*72], f32x4 (&acc)[2][8]){
  int t = threadIdx.x;
  int w=t>>6, lane=t&63, l15=lane&15, quad=lane>>4;
  #pragma unroll
  for(int s=0;s<2;s++)
    #pragma unroll
    for(int n=0;n<8;n++) acc[s][n] = (f32x4){0.f,0.f,0.f,0.f};

  float4 af[4][2]; uint4 ai[4];
  float4 bf[4][2]; uint4 bi[4];

  auto LOAD = [&](int kb){
    #pragma unroll
    for(int i=0;i<4;i++){
      int id = t + 256*i; int row = id>>3, c8 = id&7;
      if constexpr(AF32){
        const float* Ag = (const float*)Agv;
        af[i][0] = *(const float4*)&Ag[(size_t)row*lda + kb + c8*8];
        af[i][1] = *(const float4*)&Ag[(size_t)row*lda + kb + c8*8 + 4];
      } else {
        const u16* Ag = (const u16*)Agv;
        ai[i] = *(const uint4*)&Ag[(size_t)row*lda + kb + c8*8];
      }
      if constexpr(BF32){
        const float* Bg = (const float*)Bgv;
        bf[i][0] = *(const float4*)&Bg[(size_t)row*ldb + kb + c8*8];
        bf[i][1] = *(const float4*)&Bg[(size_t)row*ldb + kb + c8*8 + 4];
      } else {
        const u16* Bg = (const u16*)Bgv;
        bi[i] = *(const uint4*)&Bg[(size_t)row*ldb + kb + c8*8];
      }
    }
  };
  auto COMMIT = [&](u16* Ad, u16* Bd){
    #pragma unroll
    for(int i=0;i<4;i++){
      int id = t + 256*i; int row = id>>3, c8 = id&7;
      if constexpr(AF32){
        uint4 p = { cvt2(af[i][0].x, af[i][0].y), cvt2(af[i][0].z, af[i][0].w),
                    cvt2(af[i][1].x, af[i][1].y), cvt2(af[i][1].z, af[i][1].w) };
        *(uint4*)&Ad[row*72 + c8*8] = p;
      } else {
        *(uint4*)&Ad[row*72 + c8*8] = ai[i];
      }
      if constexpr(BF32){
        uint4 q = { cvt2(bf[i][0].x, bf[i][0].y), cvt2(bf[i][0].z, bf[i][0].w),
                    cvt2(bf[i][1].x, bf[i][1].y), cvt2(bf[i][1].z, bf[i][1].w) };
        *(uint4*)&Bd[row*72 + c8*8] = q;
      } else {
        *(uint4*)&Bd[row*72 + c8*8] = bi[i];
      }
    }
  };
  auto COMPUTE = [&](const u16* Asb, const u16* Bsb){
    #pragma unroll
    for(int ks=0; ks<2; ks++){
      short8 a[2], b[8];
      #pragma unroll
      for(int s=0;s<2;s++) a[s] = *(const short8*)&Asb[(w*32+s*16+l15)*72 + (ks*4+quad)*8];
      #pragma unroll
      for(int n=0;n<8;n++)  b[n] = *(const short8*)&Bsb[(n*16+l15)*72 + (ks*4+quad)*8];
      #pragma unroll
      for(int s=0;s<2;s++)
        #pragma unroll
        for(int n=0;n<8;n++) acc[s][n] = MFMA16(a[s], b[n], acc[s][n]);
    }
  };

  LOAD(0);  COMMIT(As[0], Bs[0]);  __syncthreads();
  LOAD(64); COMPUTE(As[0], Bs[0]); COMMIT(As[1], Bs[1]); __syncthreads();
  COMPUTE(As[1], Bs[1]);
}

// ---------------- G[d,k,v] = sum_d' projW[d,k*128+d'] Z0[v,d'], stored gbuf[d][k][v] ----------
__global__ __launch_bounds__(256) void k_gproj(const float* __restrict__ projW, const u16* __restrict__ z0,
                                               u16* __restrict__ gbuf){
  __shared__ u16 As[2][128*72], Bs[2][128*72];
  int kb = blockIdx.x >> 5, vt = blockIdx.x & 31;   // grid 96
  f32x4 acc[2][8];
  gemm_k128_t<true,false>(projW + kb*128, 3*DIM, z0 + (size_t)vt*128*DIM, DIM, As, Bs, acc);
  int t=threadIdx.x, w=t>>6, lane=t&63, l15=lane&15, quad=lane>>4;
  #pragma unroll
  for(int s=0;s<2;s++)
    #pragma unroll
    for(int n=0;n<8;n++)
      #pragma unroll
      for(int rg=0;rg<4;rg++){
        int d = w*32 + s*16 + quad*4 + rg;        // output row = (k,d) with k=kb
        int v = vt*128 + n*16 + l15;
        gbuf[(size_t)(d*KS + kb)*VN + v] = f2b(acc[s][n][rg]);
      }
}

// ---------------- diffusion GEMM: bf16 partial tiles, double-buffered & pipelined ------------
__global__ __launch_bounds__(256) void k_diff(const float* __restrict__ kers, const u16* __restrict__ gbuf,
                                              u16* __restrict__ hpart){
  __shared__ u16 As[2][128*72], Bs[2][128*72];
  int t = threadIdx.x;
  int mt = blockIdx.x & 31;     // M tile
  int sl = blockIdx.x >> 5;     // K slice 0..15 (768 each)
  int w=t>>6, lane=t&63, l15=lane&15, quad=lane>>4;
  f32x4 acc[2][8];
  #pragma unroll
  for(int s=0;s<2;s++)
    #pragma unroll
    for(int n=0;n<8;n++) acc[s][n] = (f32x4){0.f,0.f,0.f,0.f};
  int k0 = sl * 768;

  f4v  fa0[4], fa1[4];
  uint4 fb[4];

  auto LOADSTEP = [&](int step){
    int kk = k0 + step*64;
    int kout = kk >> 12; int vv = kk & 4095;      // 64-chunks never straddle the v=4096 boundary
    #pragma unroll
    for(int i=0;i<4;i++){
      int id = t + 256*i; int row = id>>3, c8 = id&7;
      const float* ap = &kers[((size_t)kout<<24) + (size_t)(mt*128+row)*VN + vv + c8*8];
      fa0[i] = __builtin_nontemporal_load((const f4v*)ap);       // streaming, no reuse
      fa1[i] = __builtin_nontemporal_load((const f4v*)(ap+4));
      fb[i]  = *(const uint4*)&gbuf[(size_t)row*KTOT + kk + c8*8];
    }
  };
  auto COMMIT = [&](u16* Ad, u16* Bd){
    #pragma unroll
    for(int i=0;i<4;i++){
      int id = t + 256*i; int row = id>>3, c8 = id&7;
      uint4 pa = { cvt2(fa0[i].x, fa0[i].y), cvt2(fa0[i].z, fa0[i].w),
                   cvt2(fa1[i].x, fa1[i].y), cvt2(fa1[i].z, fa1[i].w) };
      *(uint4*)&Ad[row*72 + c8*8] = pa;
      *(uint4*)&Bd[row*72 + c8*8] = fb[i];
    }
  };
  auto COMPUTE = [&](const u16* Asb, const u16* Bsb){
    #pragma unroll
    for(int ks=0; ks<2; ks++){
      short8 a[2], b[8];
      #pragma unroll
      for(int s=0;s<2;s++) a[s] = *(const short8*)&Asb[(w*32+s*16+l15)*72 + (ks*4+quad)*8];
      #pragma unroll
      for(int n=0;n<8;n++)  b[n] = *(const short8*)&Bsb[(n*16+l15)*72 + (ks*4+quad)*8];
      #pragma unroll
      for(int s=0;s<2;s++)
        #pragma unroll
        for(int n=0;n<8;n++) acc[s][n] = MFMA16(a[s], b[n], acc[s][n]);
    }
  };

  LOADSTEP(0);
  COMMIT(As[0], Bs[0]);
  __syncthreads();
  #pragma unroll 1
  for(int sp=0; sp<6; sp++){
    LOADSTEP(2*sp+1);
    COMPUTE(As[0], Bs[0]);
    COMMIT(As[1], Bs[1]);
    __syncthreads();
    if(sp < 5){
      LOADSTEP(2*sp+2);
      COMPUTE(As[1], Bs[1]);
      COMMIT(As[0], Bs[0]);
      __syncthreads();
    }
  }
  COMPUTE(As[1], Bs[1]);

  u16* dst = hpart + ((size_t)blockIdx.x << 14);   // 128x128 bf16 tile per block
  #pragma unroll
  for(int s=0;s<2;s++)
    #pragma unroll
    for(int n=0;n<8;n++)
      #pragma unroll
      for(int rg=0;rg<4;rg++)
        dst[(w*32+s*16+quad*4+rg)*128 + n*16 + l15] = f2b(acc[s][n][rg]);
}

// ---------------- reduce 16 bf16 partials + proj_b -> H0 f32 (vectorized uint2 loads) --------
__global__ __launch_bounds__(256) void k_hreduce(const u16* __restrict__ hpart, const float* __restrict__ pb,
                                                 float* __restrict__ h0){
  int idx = blockIdx.x*256 + threadIdx.x;   // grid 512 -> 131072 threads, 4 contiguous elems each
  int e0 = idx*4;
  int c0 = e0 & 127;
  float4 r;
  r.x = pb[c0+0]; r.y = pb[c0+1]; r.z = pb[c0+2]; r.w = pb[c0+3];
  #pragma unroll
  for(int sl=0; sl<16; sl++){
    uint2 u = *(const uint2*)&hpart[((size_t)sl<<19) + e0];
    r.x += b2f((u16)(u.x & 0xffffu)); r.y += b2f((u16)(u.x >> 16));
    r.z += b2f((u16)(u.y & 0xffffu)); r.w += b2f((u16)(u.y >> 16));
  }
  *(float4*)&h0[e0] = r;
}

// ---------------- qkv = x @ Wqkv^T + b (bf16 out); layer-0 only (A = h0 f32) ----------------
template<bool AF32>
__global__ __launch_bounds__(256) void k_qkv(const void* __restrict__ xb, const float* __restrict__ Wq,
                                             const float* __restrict__ bq, u16* __restrict__ outq){
  __shared__ u16 As[2][128*72], Bs[2][128*72];
  int mt = blockIdx.x & 31, ntile = blockIdx.x >> 5;  // grid 96
  f32x4 acc[2][8];
  const void* Ap = AF32 ? (const void*)((const float*)xb + (size_t)mt*128*DIM)
                        : (const void*)((const u16*)xb + (size_t)mt*128*DIM);
  gemm_k128_t<AF32,true>(Ap, DIM, Wq + (size_t)ntile*128*DIM, DIM, As, Bs, acc);
  int t=threadIdx.x, w=t>>6, lane=t&63, l15=lane&15, quad=lane>>4;
  #pragma unroll
  for(int s=0;s<2;s++)
    #pragma unroll
    for(int n=0;n<8;n++)
      #pragma unroll
      for(int rg=0;rg<4;rg++){
        int row = mt*128 + w*32 + s*16 + quad*4 + rg;
        int col = ntile*128 + n*16 + l15;
        outq[(size_t)row*(3*DIM) + col] = f2b(acc[s][n][rg] + bq[col]);
      }
}

// ---------------- flash attention, kt-split x2, software-pipelined K/V ----------------
// 1 barrier/iter; exact skip-rescale (alpha==1 fast path) when tile max doesn't grow.
__global__ __launch_bounds__(256) void k_attn(const u16* __restrict__ qkv, float* __restrict__ opart,
                                              float* __restrict__ mlpart){
  __shared__ u16 Qs[64*40];
  __shared__ u16 Ksh[2][128*40];
  __shared__ u16 Vt[2][32*136];
  __shared__ u16 Ps[4*16*136];
  int t=threadIdx.x;
  int b = blockIdx.x;                       // grid 512
  int h = b>>7, qt = (b>>1)&63, half = b&1;
  int w=t>>6, lane=t&63, l15=lane&15, quad=lane>>4;
  { int r = t>>2, c = t&3;
    *(uint4*)&Qs[r*40 + c*8] = *(const uint4*)&qkv[(size_t)(qt*64+r)*(3*DIM) + h*HD + c*8];
  }
  int skey = t>>2, sc4 = t&3;               // staging coords (2 iters: skey, skey+64)
  uint4 kreg[2], vreg[2];
  #pragma unroll
  for(int i=0;i<2;i++){
    int key = skey + 64*i;
    kreg[i] = *(const uint4*)&qkv[(size_t)((size_t)(half*16)*128+key)*(3*DIM) + DIM + h*HD + sc4*8];
    vreg[i] = *(const uint4*)&qkv[(size_t)((size_t)(half*16)*128+key)*(3*DIM) + 2*DIM + h*HD + sc4*8];
  }
  #pragma unroll
  for(int i=0;i<2;i++){
    int key = skey + 64*i;
    *(uint4*)&Ksh[0][key*40 + sc4*8] = kreg[i];
    u16 tmp[8]; *(uint4*)tmp = vreg[i];
    #pragma unroll
    for(int j=0;j<8;j++) Vt[0][(sc4*8+j)*136 + key] = tmp[j];
  }
  __syncthreads();
  short8 aq = *(short8*)&Qs[(w*16+l15)*40 + quad*8];
  f32x4 oacc[2]; oacc[0]=(f32x4){0.f,0.f,0.f,0.f}; oacc[1]=(f32x4){0.f,0.f,0.f,0.f};
  float mrun[4], lrun[4];
  #pragma unroll
  for(int rg=0;rg<4;rg++){ mrun[rg] = -INFINITY; lrun[rg] = 0.f; }
  const float sc = 0.17677669529663687f;  // 1/sqrt(32)
  for(int kti=0;kti<16;kti++){
    int cur = kti&1;
    if(kti<15){                             // issue next K/V global loads (no wait yet)
      int kt = half*16 + kti + 1;
      #pragma unroll
      for(int i=0;i<2;i++){
        int key = skey + 64*i;
        kreg[i] = *(const uint4*)&qkv[(size_t)(kt*128+key)*(3*DIM) + DIM + h*HD + sc4*8];
        vreg[i] = *(const uint4*)&qkv[(size_t)(kt*128+key)*(3*DIM) + 2*DIM + h*HD + sc4*8];
      }
    }
    f32x4 s[8];
    #pragma unroll
    for(int n=0;n<8;n++)
      s[n] = MFMA16(aq, *(short8*)&Ksh[cur][(n*16+l15)*40 + quad*8], ((f32x4){0.f,0.f,0.f,0.f}));
    float mx[4];
    #pragma unroll
    for(int rg=0;rg<4;rg++){
      float m = -INFINITY;
      #pragma unroll
      for(int n=0;n<8;n++) m = fmaxf(m, s[n][rg]);
      #pragma unroll
      for(int off=1;off<16;off<<=1) m = fmaxf(m, __shfl_xor(m, off, 64));
      mx[rg] = m;
    }
    // exact skip-rescale: if no row's max grew, alpha == 1 for every row -> skip the work
    bool grew = false;
    #pragma unroll
    for(int rg=0;rg<4;rg++) grew = grew || (mx[rg] > mrun[rg]);
    if(__any(grew)){
      #pragma unroll
      for(int rg=0;rg<4;rg++){
        float mn = fmaxf(mrun[rg], mx[rg]);
        float alpha = __expf(sc*(mrun[rg] - mn));   // raw-domain m, scale folded into exp
        mrun[rg] = mn;
        lrun[rg] *= alpha;
        oacc[0][rg] *= alpha; oacc[1][rg] *= alpha;
      }
    }
    float rs[4];
    #pragma unroll
    for(int rg=0;rg<4;rg++) rs[rg] = 0.f;
    #pragma unroll
    for(int n=0;n<8;n++)
      #pragma unroll
      for(int rg=0;rg<4;rg++){
        float p = __expf(sc*(s[n][rg] - mrun[rg]));
        s[n][rg] = p; rs[rg] += p;
      }
    #pragma unroll
    for(int rg=0;rg<4;rg++){
      #pragma unroll
      for(int off=1;off<16;off<<=1) rs[rg] += __shfl_xor(rs[rg], off, 64);
      lrun[rg] += rs[rg];
    }
    // P: C-layout -> LDS -> A-layout; own-wave region only, lgkmcnt wait suffices (no barrier)
    #pragma unroll
    for(int n=0;n<8;n++)
      #pragma unroll
      for(int rg=0;rg<4;rg++)
        Ps[w*16*136 + (quad*4+rg)*136 + n*16 + l15] = f2b(s[n][rg]);
    #pragma unroll
    for(int kt2=0;kt2<4;kt2++){
      short8 ap = *(short8*)&Ps[w*16*136 + l15*136 + kt2*32 + quad*8];
      #pragma unroll
      for(int n2=0;n2<2;n2++)
        oacc[n2] = MFMA16(ap, *(short8*)&Vt[cur][(n2*16+l15)*136 + kt2*32 + quad*8], oacc[n2]);
    }
    if(kti<15){                             // commit next K/V to the other LDS buffer
      #pragma unroll
      for(int i=0;i<2;i++){
        int key = skey + 64*i;
        *(uint4*)&Ksh[cur^1][key*40 + sc4*8] = kreg[i];
        u16 tmp[8]; *(uint4*)tmp = vreg[i];
        #pragma unroll
        for(int j=0;j<8;j++) Vt[cur^1][(sc4*8+j)*136 + key] = tmp[j];
      }
    }
    __syncthreads();
  }
  float* op = opart + ((size_t)b << 11);          // 64 x 32 f32
  #pragma unroll
  for(int n2=0;n2<2;n2++)
    #pragma unroll
    for(int rg=0;rg<4;rg++)
      op[(w*16+quad*4+rg)*32 + n2*16 + l15] = oacc[n2][rg];
  if(l15 == 0){
    float* ml = mlpart + ((size_t)b << 7);        // [2][64]
    #pragma unroll
    for(int rg=0;rg<4;rg++){
      int r = w*16 + quad*4 + rg;
      ml[r] = sc*mrun[rg]; ml[64 + r] = lrun[rg]; // store m in scaled domain
    }
  }
}

// ---------------- fused post-attention chain:  oproj+LN1 -> FF1+gelu -> FF2+res+LN2 (-> QKV) --
// All row-wise: each block owns 128 rows end-to-end. Intermediates pass C-layout regs ->
// own-wave LDS region -> A-fragments; LN1 output & residual stay in registers.
template<bool QKV>
__global__ __launch_bounds__(256) void k_fused(const float* __restrict__ opart, const float* __restrict__ mlpart,
                                               const float* __restrict__ Wo, const float* __restrict__ bo,
                                               const float* __restrict__ resf,
                                               const float* __restrict__ g1, const float* __restrict__ be1,
                                               const float* __restrict__ W1, const float* __restrict__ b1,
                                               const float* __restrict__ W2, const float* __restrict__ b2,
                                               const float* __restrict__ g2, const float* __restrict__ be2,
                                               float* __restrict__ outf,
                                               const float* __restrict__ Wq, const float* __restrict__ bq,
                                               u16* __restrict__ qkvout){
  __shared__ u16 As[2][128*72], Bs[2][128*72];
  int mt = blockIdx.x;   // grid 32
  int t=threadIdx.x, w=t>>6, lane=t&63, l15=lane&15, quad=lane>>4;
  f32x4 acc[2][8], y1[2][8];

  auto ZERO = [&](){
    #pragma unroll
    for(int s=0;s<2;s++)
      #pragma unroll
      for(int n=0;n<8;n++) acc[s][n] = (f32x4){0.f,0.f,0.f,0.f};
  };
  auto COMPUTE = [&](const u16* Asb, const u16* Bsb){
    #pragma unroll
    for(int ks=0; ks<2; ks++){
      short8 a[2], b[8];
      #pragma unroll
      for(int s=0;s<2;s++) a[s] = *(const short8*)&Asb[(w*32+s*16+l15)*72 + (ks*4+quad)*8];
      #pragma unroll
      for(int n=0;n<8;n++)  b[n] = *(const short8*)&Bsb[(n*16+l15)*72 + (ks*4+quad)*8];
      #pragma unroll
      for(int s=0;s<2;s++)
        #pragma unroll
        for(int n=0;n<8;n++) acc[s][n] = MFMA16(a[s], b[n], acc[s][n]);
    }
  };
  auto STAGE_W = [&](const float* __restrict__ Wp){   // 128x128 f32 row-major -> Bs (bf16)
    #pragma unroll
    for(int step=0;step<2;step++)
      #pragma unroll
      for(int i=0;i<4;i++){
        int id = t + 256*i; int row = id>>3, c8 = id&7;
        float4 f0 = *(const float4*)&Wp[(size_t)row*DIM + step*64 + c8*8];
        float4 f1 = *(const float4*)&Wp[(size_t)row*DIM + step*64 + c8*8 + 4];
        uint4 q = { cvt2(f0.x,f0.y), cvt2(f0.z,f0.w), cvt2(f1.x,f1.y), cvt2(f1.z,f1.w) };
        *(uint4*)&Bs[step][row*72 + c8*8] = q;
      }
  };
  auto WRITE_A = [&](f32x4 (&y)[2][8]){               // C-layout f32 regs -> As (A-layout bf16)
    #pragma unroll
    for(int s=0;s<2;s++)
      #pragma unroll
      for(int n=0;n<8;n++)
        #pragma unroll
        for(int rg=0;rg<4;rg++){
          int r = w*32 + s*16 + quad*4 + rg;
          As[n>>2][r*72 + (n&3)*16 + l15] = f2b(y[s][n][rg]);
        }
  };
  auto LNROW = [&](const float* __restrict__ g, const float* __restrict__ bv){
    #pragma unroll
    for(int s=0;s<2;s++)
      #pragma unroll
      for(int rg=0;rg<4;rg++){
        float a=0.f, bs=0.f;
        #pragma unroll
        for(int n=0;n<8;n++){ float x = acc[s][n][rg]; a += x; bs += x*x; }
        #pragma unroll
        for(int off=1;off<16;off<<=1){ a += __shfl_xor(a, off, 64); bs += __shfl_xor(bs, off, 64); }
        float mean = a*(1.f/128.f);
        float var  = bs*(1.f/128.f) - mean*mean;
        float rstd = rsqrtf(var + 1e-5f);
        #pragma unroll
        for(int n=0;n<8;n++){
          int col = n*16 + l15;
          acc[s][n][rg] = (acc[s][n][rg] - mean)*rstd*g[col] + bv[col];
        }
      }
  };

  // ---- phase 0: stage combined attn-O -> As, Wo -> Bs (both K-halves) ----
  #pragma unroll
  for(int step=0; step<2; step++){
    int kb = step*64;
    #pragma unroll
    for(int i=0;i<4;i++){
      int id = t + 256*i; int row = id>>3, c8 = id&7;
      int col = kb + c8*8;
      int hh = col>>5, c0 = col&31;
      int grow = mt*128 + row;
      int hq = hh*64 + (grow>>6);
      int rr = grow & 63;
      const float* o0  = opart  + ((size_t)(hq*2)   << 11);
      const float* o1  = opart  + ((size_t)(hq*2+1) << 11);
      const float* ml0 = mlpart + ((size_t)(hq*2)   << 7);
      const float* ml1 = mlpart + ((size_t)(hq*2+1) << 7);
      float m0 = ml0[rr], l0 = ml0[64+rr], m1 = ml1[rr], l1 = ml1[64+rr];
      float m = fmaxf(m0, m1);
      float w0 = __expf(m0 - m), w1 = __expf(m1 - m);
      float inv = 1.f / (l0*w0 + l1*w1);
      float4 a0  = *(const float4*)&o0[rr*32 + c0];
      float4 a1  = *(const float4*)&o0[rr*32 + c0 + 4];
      float4 c0v = *(const float4*)&o1[rr*32 + c0];
      float4 c1v = *(const float4*)&o1[rr*32 + c0 + 4];
      uint4 pa;
      pa.x = cvt2((a0.x*w0+c0v.x*w1)*inv, (a0.y*w0+c0v.y*w1)*inv);
      pa.y = cvt2((a0.z*w0+c0v.z*w1)*inv, (a0.w*w0+c0v.w*w1)*inv);
      pa.z = cvt2((a1.x*w0+c1v.x*w1)*inv, (a1.y*w0+c1v.y*w1)*inv);
      pa.w = cvt2((a1.z*w0+c1v.z*w1)*inv, (a1.w*w0+c1v.w*w1)*inv);
      *(uint4*)&As[step][row*72 + c8*8] = pa;
      float4 f0 = *(const float4*)&Wo[(size_t)row*DIM + kb + c8*8];
      float4 f1 = *(const float4*)&Wo[(size_t)row*DIM + kb + c8*8 + 4];
      uint4 qa = { cvt2(f0.x,f0.y), cvt2(f0.z,f0.w), cvt2(f1.x,f1.y), cvt2(f1.z,f1.w) };
      *(uint4*)&Bs[step][row*72 + c8*8] = qa;
    }
  }
  __syncthreads();
  // ---- GEMM1: O @ Wo^T ----
  ZERO(); COMPUTE(As[0], Bs[0]); COMPUTE(As[1], Bs[1]);
  // epilogue1: + bo + residual, LN1 -> y1 (kept in regs)
  #pragma unroll
  for(int s=0;s<2;s++)
    #pragma unroll
    for(int n=0;n<8;n++)
      #pragma unroll
      for(int rg=0;rg<4;rg++){
        int row = mt*128 + w*32 + s*16 + quad*4 + rg;
        int col = n*16 + l15;
        acc[s][n][rg] += bo[col] + resf[(size_t)row*DIM + col];
      }
  LNROW(g1, be1);
  #pragma unroll
  for(int s=0;s<2;s++)
    #pragma unroll
    for(int n=0;n<8;n++) y1[s][n] = acc[s][n];
  __syncthreads();                       // all waves done reading As/Bs of GEMM1
  WRITE_A(y1); STAGE_W(W1);
  __syncthreads();
  // ---- GEMM2: y1 @ W1^T, gelu ----
  ZERO(); COMPUTE(As[0], Bs[0]); COMPUTE(As[1], Bs[1]);
  #pragma unroll
  for(int s=0;s<2;s++)
    #pragma unroll
    for(int n=0;n<8;n++)
      #pragma unroll
      for(int rg=0;rg<4;rg++){
        int col = n*16 + l15;
        float v = acc[s][n][rg] + b1[col];
        float z = 0.7978845608028654f*(v + 0.044715f*v*v*v);
        float e = __expf(2.f*z);
        float th = 1.f - 2.f/(e + 1.f);  // tanh(z), overflow-safe
        acc[s][n][rg] = 0.5f*v*(1.f + th);
      }
  __syncthreads();
  WRITE_A(acc); STAGE_W(W2);
  __syncthreads();
  // ---- GEMM3: a2 @ W2^T + b2 + y1, LN2 ----
  ZERO(); COMPUTE(As[0], Bs[0]); COMPUTE(As[1], Bs[1]);
  #pragma unroll
  for(int s=0;s<2;s++)
    #pragma unroll
    for(int n=0;n<8;n++)
      #pragma unroll
      for(int rg=0;rg<4;rg++){
        int col = n*16 + l15;
        acc[s][n][rg] += b2[col] + y1[s][n][rg];
      }
  LNROW(g2, be2);
  #pragma unroll
  for(int s=0;s<2;s++)
    #pragma unroll
    for(int n=0;n<8;n++)
      #pragma unroll
      for(int rg=0;rg<4;rg++){
        int row = mt*128 + w*32 + s*16 + quad*4 + rg;
        int col = n*16 + l15;
        outf[(size_t)row*DIM + col] = acc[s][n][rg];
      }
  if constexpr(QKV){
    __syncthreads();                     // done reading As(a2)/Bs(W2)
    WRITE_A(acc);                        // y2 -> As
    #pragma unroll 1
    for(int nt=0; nt<3; nt++){
      STAGE_W(Wq + (size_t)nt*DIM*DIM);
      __syncthreads();
      ZERO(); COMPUTE(As[0], Bs[0]); COMPUTE(As[1], Bs[1]);
      #pragma unroll
      for(int s=0;s<2;s++)
        #pragma unroll
        for(int n=0;n<8;n++)
          #pragma unroll
          for(int rg=0;rg<4;rg++){
            int row = mt*128 + w*32 + s*16 + quad*4 + rg;
            int col = nt*128 + n*16 + l15;
            qkvout[(size_t)row*(3*DIM) + col] = f2b(acc[s][n][rg] + bq[col]);
          }
      __syncthreads();                   // before next STAGE_W overwrites Bs
    }
  }
}

// ---------------- per-visit masked mean pooling (f32 out) ----------------
__global__ __launch_bounds__(256) void k_pool(const int* __restrict__ visits, const float* __restrict__ xf,
                                              float* __restrict__ out){
  int t = threadIdx.x;
  int vis = blockIdx.x*2 + (t>>7);
  int col = t & 127;
  float s = 0.f; int cnt = 0;
  #pragma unroll
  for(int j=0;j<MAXC;j++){
    int idx = visits[vis*MAXC + j];
    if(idx != 0){ s += xf[(size_t)idx*DIM + col]; cnt++; }
  }
  float r = (cnt > 0) ? s/(float)cnt : 0.f;
  out[(size_t)vis*DIM + col] = r;
}

extern "C" void kernel_launch(void* const* d_in, const int* in_sizes, int n_in,
                              void* d_out, int out_size, void* d_ws, size_t ws_size,
                              hipStream_t stream){
  (void)in_sizes; (void)n_in; (void)out_size; (void)ws_size;
  const int*   visits = (const int*)d_in[0];
  const float* xhyp  = (const float*)d_in[1];
  const float* kers  = (const float*)d_in[2];
  const float* projW = (const float*)d_in[3];
  const float* projb = (const float*)d_in[4];
  const float* Wqkv  = (const float*)d_in[5];
  const float* bqkv  = (const float*)d_in[6];
  const float* Wo    = (const float*)d_in[7];
  const float* bo    = (const float*)d_in[8];
  const float* W1    = (const float*)d_in[9];
  const float* b1    = (const float*)d_in[10];
  const float* W2    = (const float*)d_in[11];
  const float* b2    = (const float*)d_in[12];
  const float* g1    = (const float*)d_in[13];
  const float* be1   = (const float*)d_in[14];
  const float* g2    = (const float*)d_in[15];
  const float* be2   = (const float*)d_in[16];

  char* ws = (char*)d_ws;
  u16*   z0    = (u16*)(ws);                // 1 MB : Z0 bf16 [4096][128]
  u16*   gbuf  = (u16*)(ws + (1u<<20));     // 3 MB : G bf16 [128][3][4096]
  float* h0    = (float*)(ws + (4u<<20));   // 2 MB : H0 f32
  u16*   qkvb  = (u16*)(ws + (7u<<20));     // 3 MB
  float* x1f   = (float*)(ws + (15u<<20));  // 2 MB
  float* x2f   = (float*)(ws + (18u<<20));  // 2 MB
  u16*   hpart = (u16*)(ws + (21u<<20));    // 16 MB : 512 x (128x128) bf16 partials
  float* opart = (float*)(ws + (53u<<20));  // 4 MB  : 512 x (64x32) f32
  float* mlprt = (float*)(ws + (57u<<20));  // 256 KB: 512 x [2][64] f32

  k_logmap<<<64,256,0,stream>>>(xhyp, z0);
  k_gproj<<<96,256,0,stream>>>(projW, z0, gbuf);
  k_diff<<<512,256,0,stream>>>(kers, gbuf, hpart);
  k_hreduce<<<512,256,0,stream>>>(hpart, projb, h0);

  // layer 0
  k_qkv<true><<<96,256,0,stream>>>((const void*)h0, Wqkv, bqkv, qkvb);
  k_attn<<<512,256,0,stream>>>(qkvb, opart, mlprt);
  k_fused<true><<<32,256,0,stream>>>(opart, mlprt, Wo, bo, h0, g1, be1,
                                     W1, b1, W2, b2, g2, be2, x1f,
                                     Wqkv + (size_t)3*DIM*DIM, bqkv + 3*DIM, qkvb);
  // layer 1
  k_attn<<<512,256,0,stream>>>(qkvb, opart, mlprt);
  k_fused<false><<<32,256,0,stream>>>(opart, mlprt, Wo + (size_t)DIM*DIM, bo + DIM, x1f,
                                      g1 + DIM, be1 + DIM, W1 + (size_t)DIM*DIM, b1 + DIM,
                                      W2 + (size_t)DIM*DIM, b2 + DIM, g2 + DIM, be2 + DIM, x2f,
                                      nullptr, nullptr, nullptr);
  k_pool<<<4096,256,0,stream>>>(visits, x2f, (float*)d_out);
}

// Round 3
// 760.586 us; speedup vs baseline: 1.0438x; 1.0438x over previous
//
#include <hip/hip_runtime.h>
#include <hip/hip_bf16.h>
#include <math.h>

#define VN 4096
#define DIM 128
#define KS 3
#define NH 4
#define HD 32
#define NVIS 8192
#define MAXC 32
#define KTOT (KS*VN)   // 12288

typedef unsigned short u16;
typedef __attribute__((ext_vector_type(8))) short short8;   // 8 bf16 (4 VGPRs)
typedef __attribute__((ext_vector_type(4))) float f32x4;
typedef __attribute__((ext_vector_type(4))) float f4v;      // for nontemporal loads

__device__ __forceinline__ u16 f2b(float f){
  union { float f; unsigned u; } c; c.f = f;
  unsigned u = c.u;
  return (u16)((u + 0x7fffu + ((u >> 16) & 1u)) >> 16);   // RTNE
}
__device__ __forceinline__ float b2f(u16 x){
  union { float f; unsigned u; } c; c.u = ((unsigned)x) << 16; return c.f;
}
// packed f32x2 -> bf16x2 (RTNE), dst.lo = lo, dst.hi = hi
__device__ __forceinline__ unsigned cvt2(float lo, float hi){
  unsigned r;
  asm("v_cvt_pk_bf16_f32 %0, %1, %2" : "=v"(r) : "v"(lo), "v"(hi));
  return r;
}
#define MFMA16(a,b,c) __builtin_amdgcn_mfma_f32_16x16x32_bf16((a),(b),(c),0,0,0)

// ---------------- logmap0 (f32 in, bf16 out):  Z0 = artanh(||x||)/||x|| * x ----------------
__global__ __launch_bounds__(256) void k_logmap(const float* __restrict__ xh, u16* __restrict__ z0){
  __shared__ float xs[64][132];
  __shared__ float part[4][64];
  __shared__ float sscale[64];
  int t = threadIdx.x;
  int v0 = blockIdx.x * 64;
  #pragma unroll
  for(int i=0;i<8;i++){
    int id = t + 256*i; int e = id*4; int r = e>>7; int c = e&127;
    float4 u = *(const float4*)&xh[(size_t)(v0+r)*DIM + c];
    xs[r][c+0]=u.x; xs[r][c+1]=u.y; xs[r][c+2]=u.z; xs[r][c+3]=u.w;
  }
  __syncthreads();
  int r = t & 63, q = t >> 6;
  float p = 0.f;
  #pragma unroll
  for(int c=0;c<32;c++){ float x = xs[r][q*32+c]; p += x*x; }
  part[q][r] = p;
  __syncthreads();
  if(t < 64){
    float ss = part[0][t]+part[1][t]+part[2][t]+part[3][t];
    float n = sqrtf(ss);
    float nc = fminf(fmaxf(n, 1e-7f), 1.0f - 1e-5f);
    sscale[t] = atanhf(nc) / fmaxf(n, 1e-7f);
  }
  __syncthreads();
  #pragma unroll
  for(int i=0;i<8;i++){
    int id = t + 256*i; int e = id*4; int rr = e>>7; int cc = e&127;
    float s = sscale[rr];
    uint2 o = { cvt2(xs[rr][cc+0]*s, xs[rr][cc+1]*s),
                cvt2(xs[rr][cc+2]*s, xs[rr][cc+3]*s) };
    *(uint2*)&z0[(size_t)(v0+rr)*DIM + cc] = o;
  }
}

// ---------------- shared 128x128-tile GEMM core, K=128 (BK=64 x 2), pipelined ----------------
template<bool AF32, bool BF32>
__device__ __forceinline__ void gemm_k128_t(const void* __restrict__ Agv, int lda,
                                            const void* __restrict__ Bgv, int ldb,
                                            u16 (*As)[128*72], u16 (*Bs)[128*72], f32x4 (&acc)[2][8]){
  int t = threadIdx.x;
  int w=t>>6, lane=t&63, l15=lane&15, quad=lane>>4;
  #pragma unroll
  for(int s=0;s<2;s++)
    #pragma unroll
    for(int n=0;n<8;n++) acc[s][n] = (f32x4){0.f,0.f,0.f,0.f};

  float4 af[4][2]; uint4 ai[4];
  float4 bf[4][2]; uint4 bi[4];

  auto LOAD = [&](int kb){
    #pragma unroll
    for(int i=0;i<4;i++){
      int id = t + 256*i; int row = id>>3, c8 = id&7;
      if constexpr(AF32){
        const float* Ag = (const float*)Agv;
        af[i][0] = *(const float4*)&Ag[(size_t)row*lda + kb + c8*8];
        af[i][1] = *(const float4*)&Ag[(size_t)row*lda + kb + c8*8 + 4];
      } else {
        const u16* Ag = (const u16*)Agv;
        ai[i] = *(const uint4*)&Ag[(size_t)row*lda + kb + c8*8];
      }
      if constexpr(BF32){
        const float* Bg = (const float*)Bgv;
        bf[i][0] = *(const float4*)&Bg[(size_t)row*ldb + kb + c8*8];
        bf[i][1] = *(const float4*)&Bg[(size_t)row*ldb + kb + c8*8 + 4];
      } else {
        const u16* Bg = (const u16*)Bgv;
        bi[i] = *(const uint4*)&Bg[(size_t)row*ldb + kb + c8*8];
      }
    }
  };
  auto COMMIT = [&](u16* Ad, u16* Bd){
    #pragma unroll
    for(int i=0;i<4;i++){
      int id = t + 256*i; int row = id>>3, c8 = id&7;
      if constexpr(AF32){
        uint4 p = { cvt2(af[i][0].x, af[i][0].y), cvt2(af[i][0].z, af[i][0].w),
                    cvt2(af[i][1].x, af[i][1].y), cvt2(af[i][1].z, af[i][1].w) };
        *(uint4*)&Ad[row*72 + c8*8] = p;
      } else {
        *(uint4*)&Ad[row*72 + c8*8] = ai[i];
      }
      if constexpr(BF32){
        uint4 q = { cvt2(bf[i][0].x, bf[i][0].y), cvt2(bf[i][0].z, bf[i][0].w),
                    cvt2(bf[i][1].x, bf[i][1].y), cvt2(bf[i][1].z, bf[i][1].w) };
        *(uint4*)&Bd[row*72 + c8*8] = q;
      } else {
        *(uint4*)&Bd[row*72 + c8*8] = bi[i];
      }
    }
  };
  auto COMPUTE = [&](const u16* Asb, const u16* Bsb){
    #pragma unroll
    for(int ks=0; ks<2; ks++){
      short8 a[2], b[8];
      #pragma unroll
      for(int s=0;s<2;s++) a[s] = *(const short8*)&Asb[(w*32+s*16+l15)*72 + (ks*4+quad)*8];
      #pragma unroll
      for(int n=0;n<8;n++)  b[n] = *(const short8*)&Bsb[(n*16+l15)*72 + (ks*4+quad)*8];
      #pragma unroll
      for(int s=0;s<2;s++)
        #pragma unroll
        for(int n=0;n<8;n++) acc[s][n] = MFMA16(a[s], b[n], acc[s][n]);
    }
  };

  LOAD(0);  COMMIT(As[0], Bs[0]);  __syncthreads();
  LOAD(64); COMPUTE(As[0], Bs[0]); COMMIT(As[1], Bs[1]); __syncthreads();
  COMPUTE(As[1], Bs[1]);
}

// ---------------- G[d,k,v] = sum_d' projW[d,k*128+d'] Z0[v,d'], stored gbuf[d][k][v] ----------
__global__ __launch_bounds__(256) void k_gproj(const float* __restrict__ projW, const u16* __restrict__ z0,
                                               u16* __restrict__ gbuf){
  __shared__ u16 As[2][128*72], Bs[2][128*72];
  int kb = blockIdx.x >> 5, vt = blockIdx.x & 31;   // grid 96
  f32x4 acc[2][8];
  gemm_k128_t<true,false>(projW + kb*128, 3*DIM, z0 + (size_t)vt*128*DIM, DIM, As, Bs, acc);
  int t=threadIdx.x, w=t>>6, lane=t&63, l15=lane&15, quad=lane>>4;
  #pragma unroll
  for(int s=0;s<2;s++)
    #pragma unroll
    for(int n=0;n<8;n++)
      #pragma unroll
      for(int rg=0;rg<4;rg++){
        int d = w*32 + s*16 + quad*4 + rg;        // output row = (k,d) with k=kb
        int v = vt*128 + n*16 + l15;
        gbuf[(size_t)(d*KS + kb)*VN + v] = f2b(acc[s][n][rg]);
      }
}

// ---------------- diffusion GEMM: bf16 partial tiles, double-buffered & pipelined ------------
__global__ __launch_bounds__(256) void k_diff(const float* __restrict__ kers, const u16* __restrict__ gbuf,
                                              u16* __restrict__ hpart){
  __shared__ u16 As[2][128*72], Bs[2][128*72];
  int t = threadIdx.x;
  int mt = blockIdx.x & 31;     // M tile
  int sl = blockIdx.x >> 5;     // K slice 0..15 (768 each)
  int w=t>>6, lane=t&63, l15=lane&15, quad=lane>>4;
  f32x4 acc[2][8];
  #pragma unroll
  for(int s=0;s<2;s++)
    #pragma unroll
    for(int n=0;n<8;n++) acc[s][n] = (f32x4){0.f,0.f,0.f,0.f};
  int k0 = sl * 768;

  f4v  fa0[4], fa1[4];
  uint4 fb[4];

  auto LOADSTEP = [&](int step){
    int kk = k0 + step*64;
    int kout = kk >> 12; int vv = kk & 4095;      // 64-chunks never straddle the v=4096 boundary
    #pragma unroll
    for(int i=0;i<4;i++){
      int id = t + 256*i; int row = id>>3, c8 = id&7;
      const float* ap = &kers[((size_t)kout<<24) + (size_t)(mt*128+row)*VN + vv + c8*8];
      fa0[i] = __builtin_nontemporal_load((const f4v*)ap);       // streaming, no reuse
      fa1[i] = __builtin_nontemporal_load((const f4v*)(ap+4));
      fb[i]  = *(const uint4*)&gbuf[(size_t)row*KTOT + kk + c8*8];
    }
  };
  auto COMMIT = [&](u16* Ad, u16* Bd){
    #pragma unroll
    for(int i=0;i<4;i++){
      int id = t + 256*i; int row = id>>3, c8 = id&7;
      uint4 pa = { cvt2(fa0[i].x, fa0[i].y), cvt2(fa0[i].z, fa0[i].w),
                   cvt2(fa1[i].x, fa1[i].y), cvt2(fa1[i].z, fa1[i].w) };
      *(uint4*)&Ad[row*72 + c8*8] = pa;
      *(uint4*)&Bd[row*72 + c8*8] = fb[i];
    }
  };
  auto COMPUTE = [&](const u16* Asb, const u16* Bsb){
    #pragma unroll
    for(int ks=0; ks<2; ks++){
      short8 a[2], b[8];
      #pragma unroll
      for(int s=0;s<2;s++) a[s] = *(const short8*)&Asb[(w*32+s*16+l15)*72 + (ks*4+quad)*8];
      #pragma unroll
      for(int n=0;n<8;n++)  b[n] = *(const short8*)&Bsb[(n*16+l15)*72 + (ks*4+quad)*8];
      #pragma unroll
      for(int s=0;s<2;s++)
        #pragma unroll
        for(int n=0;n<8;n++) acc[s][n] = MFMA16(a[s], b[n], acc[s][n]);
    }
  };

  LOADSTEP(0);
  COMMIT(As[0], Bs[0]);
  __syncthreads();
  #pragma unroll 1
  for(int sp=0; sp<6; sp++){
    LOADSTEP(2*sp+1);
    COMPUTE(As[0], Bs[0]);
    COMMIT(As[1], Bs[1]);
    __syncthreads();
    if(sp < 5){
      LOADSTEP(2*sp+2);
      COMPUTE(As[1], Bs[1]);
      COMMIT(As[0], Bs[0]);
      __syncthreads();
    }
  }
  COMPUTE(As[1], Bs[1]);

  u16* dst = hpart + ((size_t)blockIdx.x << 14);   // 128x128 bf16 tile per block
  #pragma unroll
  for(int s=0;s<2;s++)
    #pragma unroll
    for(int n=0;n<8;n++)
      #pragma unroll
      for(int rg=0;rg<4;rg++)
        dst[(w*32+s*16+quad*4+rg)*128 + n*16 + l15] = f2b(acc[s][n][rg]);
}

// ---------------- reduce 16 bf16 partials + proj_b -> H0 f32 (vectorized uint2 loads) --------
__global__ __launch_bounds__(256) void k_hreduce(const u16* __restrict__ hpart, const float* __restrict__ pb,
                                                 float* __restrict__ h0){
  int idx = blockIdx.x*256 + threadIdx.x;   // grid 512 -> 131072 threads, 4 contiguous elems each
  int e0 = idx*4;
  int c0 = e0 & 127;
  float4 r;
  r.x = pb[c0+0]; r.y = pb[c0+1]; r.z = pb[c0+2]; r.w = pb[c0+3];
  #pragma unroll
  for(int sl=0; sl<16; sl++){
    uint2 u = *(const uint2*)&hpart[((size_t)sl<<19) + e0];
    r.x += b2f((u16)(u.x & 0xffffu)); r.y += b2f((u16)(u.x >> 16));
    r.z += b2f((u16)(u.y & 0xffffu)); r.w += b2f((u16)(u.y >> 16));
  }
  *(float4*)&h0[e0] = r;
}

// ---------------- qkv = x @ Wqkv^T + b (bf16 out); layer-0 only (A = h0 f32) ----------------
template<bool AF32>
__global__ __launch_bounds__(256) void k_qkv(const void* __restrict__ xb, const float* __restrict__ Wq,
                                             const float* __restrict__ bq, u16* __restrict__ outq){
  __shared__ u16 As[2][128*72], Bs[2][128*72];
  int mt = blockIdx.x & 31, ntile = blockIdx.x >> 5;  // grid 96
  f32x4 acc[2][8];
  const void* Ap = AF32 ? (const void*)((const float*)xb + (size_t)mt*128*DIM)
                        : (const void*)((const u16*)xb + (size_t)mt*128*DIM);
  gemm_k128_t<AF32,true>(Ap, DIM, Wq + (size_t)ntile*128*DIM, DIM, As, Bs, acc);
  int t=threadIdx.x, w=t>>6, lane=t&63, l15=lane&15, quad=lane>>4;
  #pragma unroll
  for(int s=0;s<2;s++)
    #pragma unroll
    for(int n=0;n<8;n++)
      #pragma unroll
      for(int rg=0;rg<4;rg++){
        int row = mt*128 + w*32 + s*16 + quad*4 + rg;
        int col = ntile*128 + n*16 + l15;
        outq[(size_t)row*(3*DIM) + col] = f2b(acc[s][n][rg] + bq[col]);
      }
}

// ---------------- flash attention, kt-split x2, software-pipelined K/V ----------------
// 1 barrier/iter; exact skip-rescale (alpha==1 fast path) when tile max doesn't grow.
__global__ __launch_bounds__(256) void k_attn(const u16* __restrict__ qkv, float* __restrict__ opart,
                                              float* __restrict__ mlpart){
  __shared__ u16 Qs[64*40];
  __shared__ u16 Ksh[2][128*40];
  __shared__ u16 Vt[2][32*136];
  __shared__ u16 Ps[4*16*136];
  int t=threadIdx.x;
  int b = blockIdx.x;                       // grid 512
  int h = b>>7, qt = (b>>1)&63, half = b&1;
  int w=t>>6, lane=t&63, l15=lane&15, quad=lane>>4;
  { int r = t>>2, c = t&3;
    *(uint4*)&Qs[r*40 + c*8] = *(const uint4*)&qkv[(size_t)(qt*64+r)*(3*DIM) + h*HD + c*8];
  }
  int skey = t>>2, sc4 = t&3;               // staging coords (2 iters: skey, skey+64)
  uint4 kreg[2], vreg[2];
  #pragma unroll
  for(int i=0;i<2;i++){
    int key = skey + 64*i;
    kreg[i] = *(const uint4*)&qkv[(size_t)((size_t)(half*16)*128+key)*(3*DIM) + DIM + h*HD + sc4*8];
    vreg[i] = *(const uint4*)&qkv[(size_t)((size_t)(half*16)*128+key)*(3*DIM) + 2*DIM + h*HD + sc4*8];
  }
  #pragma unroll
  for(int i=0;i<2;i++){
    int key = skey + 64*i;
    *(uint4*)&Ksh[0][key*40 + sc4*8] = kreg[i];
    u16 tmp[8]; *(uint4*)tmp = vreg[i];
    #pragma unroll
    for(int j=0;j<8;j++) Vt[0][(sc4*8+j)*136 + key] = tmp[j];
  }
  __syncthreads();
  short8 aq = *(short8*)&Qs[(w*16+l15)*40 + quad*8];
  f32x4 oacc[2]; oacc[0]=(f32x4){0.f,0.f,0.f,0.f}; oacc[1]=(f32x4){0.f,0.f,0.f,0.f};
  float mrun[4], lrun[4];
  #pragma unroll
  for(int rg=0;rg<4;rg++){ mrun[rg] = -INFINITY; lrun[rg] = 0.f; }
  const float sc = 0.17677669529663687f;  // 1/sqrt(32)
  for(int kti=0;kti<16;kti++){
    int cur = kti&1;
    if(kti<15){                             // issue next K/V global loads (no wait yet)
      int kt = half*16 + kti + 1;
      #pragma unroll
      for(int i=0;i<2;i++){
        int key = skey + 64*i;
        kreg[i] = *(const uint4*)&qkv[(size_t)(kt*128+key)*(3*DIM) + DIM + h*HD + sc4*8];
        vreg[i] = *(const uint4*)&qkv[(size_t)(kt*128+key)*(3*DIM) + 2*DIM + h*HD + sc4*8];
      }
    }
    f32x4 s[8];
    #pragma unroll
    for(int n=0;n<8;n++)
      s[n] = MFMA16(aq, *(short8*)&Ksh[cur][(n*16+l15)*40 + quad*8], ((f32x4){0.f,0.f,0.f,0.f}));
    float mx[4];
    #pragma unroll
    for(int rg=0;rg<4;rg++){
      float m = -INFINITY;
      #pragma unroll
      for(int n=0;n<8;n++) m = fmaxf(m, s[n][rg]);
      #pragma unroll
      for(int off=1;off<16;off<<=1) m = fmaxf(m, __shfl_xor(m, off, 64));
      mx[rg] = m;
    }
    // exact skip-rescale: if no row's max grew, alpha == 1 for every row -> skip the work
    bool grew = false;
    #pragma unroll
    for(int rg=0;rg<4;rg++) grew = grew || (mx[rg] > mrun[rg]);
    if(__any(grew)){
      #pragma unroll
      for(int rg=0;rg<4;rg++){
        float mn = fmaxf(mrun[rg], mx[rg]);
        float alpha = __expf(sc*(mrun[rg] - mn));   // raw-domain m, scale folded into exp
        mrun[rg] = mn;
        lrun[rg] *= alpha;
        oacc[0][rg] *= alpha; oacc[1][rg] *= alpha;
      }
    }
    float rs[4];
    #pragma unroll
    for(int rg=0;rg<4;rg++) rs[rg] = 0.f;
    #pragma unroll
    for(int n=0;n<8;n++)
      #pragma unroll
      for(int rg=0;rg<4;rg++){
        float p = __expf(sc*(s[n][rg] - mrun[rg]));
        s[n][rg] = p; rs[rg] += p;
      }
    #pragma unroll
    for(int rg=0;rg<4;rg++){
      #pragma unroll
      for(int off=1;off<16;off<<=1) rs[rg] += __shfl_xor(rs[rg], off, 64);
      lrun[rg] += rs[rg];
    }
    // P: C-layout -> LDS -> A-layout; own-wave region only, lgkmcnt wait suffices (no barrier)
    #pragma unroll
    for(int n=0;n<8;n++)
      #pragma unroll
      for(int rg=0;rg<4;rg++)
        Ps[w*16*136 + (quad*4+rg)*136 + n*16 + l15] = f2b(s[n][rg]);
    #pragma unroll
    for(int kt2=0;kt2<4;kt2++){
      short8 ap = *(short8*)&Ps[w*16*136 + l15*136 + kt2*32 + quad*8];
      #pragma unroll
      for(int n2=0;n2<2;n2++)
        oacc[n2] = MFMA16(ap, *(short8*)&Vt[cur][(n2*16+l15)*136 + kt2*32 + quad*8], oacc[n2]);
    }
    if(kti<15){                             // commit next K/V to the other LDS buffer
      #pragma unroll
      for(int i=0;i<2;i++){
        int key = skey + 64*i;
        *(uint4*)&Ksh[cur^1][key*40 + sc4*8] = kreg[i];
        u16 tmp[8]; *(uint4*)tmp = vreg[i];
        #pragma unroll
        for(int j=0;j<8;j++) Vt[cur^1][(sc4*8+j)*136 + key] = tmp[j];
      }
    }
    __syncthreads();
  }
  float* op = opart + ((size_t)b << 11);          // 64 x 32 f32
  #pragma unroll
  for(int n2=0;n2<2;n2++)
    #pragma unroll
    for(int rg=0;rg<4;rg++)
      op[(w*16+quad*4+rg)*32 + n2*16 + l15] = oacc[n2][rg];
  if(l15 == 0){
    float* ml = mlpart + ((size_t)b << 7);        // [2][64]
    #pragma unroll
    for(int rg=0;rg<4;rg++){
      int r = w*16 + quad*4 + rg;
      ml[r] = sc*mrun[rg]; ml[64 + r] = lrun[rg]; // store m in scaled domain
    }
  }
}

// ---------------- fused post-attention chain:  oproj+LN1 -> FF1+gelu -> FF2+res+LN2 (-> QKV) --
// Register-pressure-safe version: launch_bounds(256,1) lifts the VGPR cap; the LN1 result
// (residual for GEMM3) is stashed in LDS (same-thread write/read) instead of 64 VGPRs.
template<bool QKV>
__global__ __launch_bounds__(256, 1) void k_fused(const float* __restrict__ opart, const float* __restrict__ mlpart,
                                               const float* __restrict__ Wo, const float* __restrict__ bo,
                                               const float* __restrict__ resf,
                                               const float* __restrict__ g1, const float* __restrict__ be1,
                                               const float* __restrict__ W1, const float* __restrict__ b1,
                                               const float* __restrict__ W2, const float* __restrict__ b2,
                                               const float* __restrict__ g2, const float* __restrict__ be2,
                                               float* __restrict__ outf,
                                               const float* __restrict__ Wq, const float* __restrict__ bq,
                                               u16* __restrict__ qkvout){
  __shared__ u16 As[2][128*72], Bs[2][128*72];
  __shared__ float y1f[128*132];   // LN1 output (f32 residual for GEMM3); 66 KB
  int mt = blockIdx.x;   // grid 32
  int t=threadIdx.x, w=t>>6, lane=t&63, l15=lane&15, quad=lane>>4;
  f32x4 acc[2][8];

  auto ZERO = [&](){
    #pragma unroll
    for(int s=0;s<2;s++)
      #pragma unroll
      for(int n=0;n<8;n++) acc[s][n] = (f32x4){0.f,0.f,0.f,0.f};
  };
  auto COMPUTE = [&](const u16* Asb, const u16* Bsb){
    #pragma unroll
    for(int ks=0; ks<2; ks++){
      short8 a[2], b[8];
      #pragma unroll
      for(int s=0;s<2;s++) a[s] = *(const short8*)&Asb[(w*32+s*16+l15)*72 + (ks*4+quad)*8];
      #pragma unroll
      for(int n=0;n<8;n++)  b[n] = *(const short8*)&Bsb[(n*16+l15)*72 + (ks*4+quad)*8];
      #pragma unroll
      for(int s=0;s<2;s++)
        #pragma unroll
        for(int n=0;n<8;n++) acc[s][n] = MFMA16(a[s], b[n], acc[s][n]);
    }
  };
  auto STAGE_W = [&](const float* __restrict__ Wp){   // 128x128 f32 row-major -> Bs (bf16)
    #pragma unroll
    for(int step=0;step<2;step++)
      #pragma unroll
      for(int i=0;i<4;i++){
        int id = t + 256*i; int row = id>>3, c8 = id&7;
        float4 f0 = *(const float4*)&Wp[(size_t)row*DIM + step*64 + c8*8];
        float4 f1 = *(const float4*)&Wp[(size_t)row*DIM + step*64 + c8*8 + 4];
        uint4 q = { cvt2(f0.x,f0.y), cvt2(f0.z,f0.w), cvt2(f1.x,f1.y), cvt2(f1.z,f1.w) };
        *(uint4*)&Bs[step][row*72 + c8*8] = q;
      }
  };
  auto WRITE_A = [&](){               // C-layout f32 acc -> As (A-layout bf16)
    #pragma unroll
    for(int s=0;s<2;s++)
      #pragma unroll
      for(int n=0;n<8;n++)
        #pragma unroll
        for(int rg=0;rg<4;rg++){
          int r = w*32 + s*16 + quad*4 + rg;
          As[n>>2][r*72 + (n&3)*16 + l15] = f2b(acc[s][n][rg]);
        }
  };
  auto LNROW = [&](const float* __restrict__ g, const float* __restrict__ bv){
    #pragma unroll
    for(int s=0;s<2;s++)
      #pragma unroll
      for(int rg=0;rg<4;rg++){
        float a=0.f, bs=0.f;
        #pragma unroll
        for(int n=0;n<8;n++){ float x = acc[s][n][rg]; a += x; bs += x*x; }
        #pragma unroll
        for(int off=1;off<16;off<<=1){ a += __shfl_xor(a, off, 64); bs += __shfl_xor(bs, off, 64); }
        float mean = a*(1.f/128.f);
        float var  = bs*(1.f/128.f) - mean*mean;
        float rstd = rsqrtf(var + 1e-5f);
        #pragma unroll
        for(int n=0;n<8;n++){
          int col = n*16 + l15;
          acc[s][n][rg] = (acc[s][n][rg] - mean)*rstd*g[col] + bv[col];
        }
      }
  };

  // ---- phase 0: stage combined attn-O -> As, Wo -> Bs (both K-halves) ----
  #pragma unroll
  for(int step=0; step<2; step++){
    int kb = step*64;
    #pragma unroll
    for(int i=0;i<4;i++){
      int id = t + 256*i; int row = id>>3, c8 = id&7;
      int col = kb + c8*8;
      int hh = col>>5, c0 = col&31;
      int grow = mt*128 + row;
      int hq = hh*64 + (grow>>6);
      int rr = grow & 63;
      const float* o0  = opart  + ((size_t)(hq*2)   << 11);
      const float* o1  = opart  + ((size_t)(hq*2+1) << 11);
      const float* ml0 = mlpart + ((size_t)(hq*2)   << 7);
      const float* ml1 = mlpart + ((size_t)(hq*2+1) << 7);
      float m0 = ml0[rr], l0 = ml0[64+rr], m1 = ml1[rr], l1 = ml1[64+rr];
      float m = fmaxf(m0, m1);
      float w0 = __expf(m0 - m), w1 = __expf(m1 - m);
      float inv = 1.f / (l0*w0 + l1*w1);
      float4 a0  = *(const float4*)&o0[rr*32 + c0];
      float4 a1  = *(const float4*)&o0[rr*32 + c0 + 4];
      float4 c0v = *(const float4*)&o1[rr*32 + c0];
      float4 c1v = *(const float4*)&o1[rr*32 + c0 + 4];
      uint4 pa;
      pa.x = cvt2((a0.x*w0+c0v.x*w1)*inv, (a0.y*w0+c0v.y*w1)*inv);
      pa.y = cvt2((a0.z*w0+c0v.z*w1)*inv, (a0.w*w0+c0v.w*w1)*inv);
      pa.z = cvt2((a1.x*w0+c1v.x*w1)*inv, (a1.y*w0+c1v.y*w1)*inv);
      pa.w = cvt2((a1.z*w0+c1v.z*w1)*inv, (a1.w*w0+c1v.w*w1)*inv);
      *(uint4*)&As[step][row*72 + c8*8] = pa;
      float4 f0 = *(const float4*)&Wo[(size_t)row*DIM + kb + c8*8];
      float4 f1 = *(const float4*)&Wo[(size_t)row*DIM + kb + c8*8 + 4];
      uint4 qa = { cvt2(f0.x,f0.y), cvt2(f0.z,f0.w), cvt2(f1.x,f1.y), cvt2(f1.z,f1.w) };
      *(uint4*)&Bs[step][row*72 + c8*8] = qa;
    }
  }
  __syncthreads();
  // ---- GEMM1: O @ Wo^T ----
  ZERO(); COMPUTE(As[0], Bs[0]); COMPUTE(As[1], Bs[1]);
  // epilogue1: + bo + residual, LN1 -> y1f (LDS stash, same-thread access)
  #pragma unroll
  for(int s=0;s<2;s++)
    #pragma unroll
    for(int n=0;n<8;n++)
      #pragma unroll
      for(int rg=0;rg<4;rg++){
        int row = mt*128 + w*32 + s*16 + quad*4 + rg;
        int col = n*16 + l15;
        acc[s][n][rg] += bo[col] + resf[(size_t)row*DIM + col];
      }
  LNROW(g1, be1);
  #pragma unroll
  for(int s=0;s<2;s++)
    #pragma unroll
    for(int n=0;n<8;n++)
      #pragma unroll
      for(int rg=0;rg<4;rg++){
        int r = w*32 + s*16 + quad*4 + rg;
        y1f[r*132 + n*16 + l15] = acc[s][n][rg];
      }
  __syncthreads();                       // all waves done reading As/Bs of GEMM1
  WRITE_A(); STAGE_W(W1);
  __syncthreads();
  // ---- GEMM2: y1 @ W1^T, gelu ----
  ZERO(); COMPUTE(As[0], Bs[0]); COMPUTE(As[1], Bs[1]);
  #pragma unroll
  for(int s=0;s<2;s++)
    #pragma unroll
    for(int n=0;n<8;n++)
      #pragma unroll
      for(int rg=0;rg<4;rg++){
        int col = n*16 + l15;
        float v = acc[s][n][rg] + b1[col];
        float z = 0.7978845608028654f*(v + 0.044715f*v*v*v);
        float e = __expf(2.f*z);
        float th = 1.f - 2.f/(e + 1.f);  // tanh(z), overflow-safe
        acc[s][n][rg] = 0.5f*v*(1.f + th);
      }
  __syncthreads();
  WRITE_A(); STAGE_W(W2);
  __syncthreads();
  // ---- GEMM3: a2 @ W2^T + b2 + y1, LN2 ----
  ZERO(); COMPUTE(As[0], Bs[0]); COMPUTE(As[1], Bs[1]);
  #pragma unroll
  for(int s=0;s<2;s++)
    #pragma unroll
    for(int n=0;n<8;n++)
      #pragma unroll
      for(int rg=0;rg<4;rg++){
        int r = w*32 + s*16 + quad*4 + rg;
        int col = n*16 + l15;
        acc[s][n][rg] += b2[col] + y1f[r*132 + col];
      }
  LNROW(g2, be2);
  #pragma unroll
  for(int s=0;s<2;s++)
    #pragma unroll
    for(int n=0;n<8;n++)
      #pragma unroll
      for(int rg=0;rg<4;rg++){
        int row = mt*128 + w*32 + s*16 + quad*4 + rg;
        int col = n*16 + l15;
        outf[(size_t)row*DIM + col] = acc[s][n][rg];
      }
  if constexpr(QKV){
    __syncthreads();                     // done reading As(a2)/Bs(W2)
    WRITE_A();                           // y2 -> As
    #pragma unroll 1
    for(int nt=0; nt<3; nt++){
      STAGE_W(Wq + (size_t)nt*DIM*DIM);
      __syncthreads();
      ZERO(); COMPUTE(As[0], Bs[0]); COMPUTE(As[1], Bs[1]);
      #pragma unroll
      for(int s=0;s<2;s++)
        #pragma unroll
        for(int n=0;n<8;n++)
          #pragma unroll
          for(int rg=0;rg<4;rg++){
            int row = mt*128 + w*32 + s*16 + quad*4 + rg;
            int col = nt*128 + n*16 + l15;
            qkvout[(size_t)row*(3*DIM) + col] = f2b(acc[s][n][rg] + bq[col]);
          }
      __syncthreads();                   // before next STAGE_W overwrites Bs
    }
  }
}

// ---------------- per-visit masked mean pooling (f32 out) ----------------
__global__ __launch_bounds__(256) void k_pool(const int* __restrict__ visits, const float* __restrict__ xf,
                                              float* __restrict__ out){
  int t = threadIdx.x;
  int vis = blockIdx.x*2 + (t>>7);
  int col = t & 127;
  float s = 0.f; int cnt = 0;
  #pragma unroll
  for(int j=0;j<MAXC;j++){
    int idx = visits[vis*MAXC + j];
    if(idx != 0){ s += xf[(size_t)idx*DIM + col]; cnt++; }
  }
  float r = (cnt > 0) ? s/(float)cnt : 0.f;
  out[(size_t)vis*DIM + col] = r;
}

extern "C" void kernel_launch(void* const* d_in, const int* in_sizes, int n_in,
                              void* d_out, int out_size, void* d_ws, size_t ws_size,
                              hipStream_t stream){
  (void)in_sizes; (void)n_in; (void)out_size; (void)ws_size;
  const int*   visits = (const int*)d_in[0];
  const float* xhyp  = (const float*)d_in[1];
  const float* kers  = (const float*)d_in[2];
  const float* projW = (const float*)d_in[3];
  const float* projb = (const float*)d_in[4];
  const float* Wqkv  = (const float*)d_in[5];
  const float* bqkv  = (const float*)d_in[6];
  const float* Wo    = (const float*)d_in[7];
  const float* bo    = (const float*)d_in[8];
  const float* W1    = (const float*)d_in[9];
  const float* b1    = (const float*)d_in[10];
  const float* W2    = (const float*)d_in[11];
  const float* b2    = (const float*)d_in[12];
  const float* g1    = (const float*)d_in[13];
  const float* be1   = (const float*)d_in[14];
  const float* g2    = (const float*)d_in[15];
  const float* be2   = (const float*)d_in[16];

  char* ws = (char*)d_ws;
  u16*   z0    = (u16*)(ws);                // 1 MB : Z0 bf16 [4096][128]
  u16*   gbuf  = (u16*)(ws + (1u<<20));     // 3 MB : G bf16 [128][3][4096]
  float* h0    = (float*)(ws + (4u<<20));   // 2 MB : H0 f32
  u16*   qkvb  = (u16*)(ws + (7u<<20));     // 3 MB
  float* x1f   = (float*)(ws + (15u<<20));  // 2 MB
  float* x2f   = (float*)(ws + (18u<<20));  // 2 MB
  u16*   hpart = (u16*)(ws + (21u<<20));    // 16 MB : 512 x (128x128) bf16 partials
  float* opart = (float*)(ws + (53u<<20));  // 4 MB  : 512 x (64x32) f32
  float* mlprt = (float*)(ws + (57u<<20));  // 256 KB: 512 x [2][64] f32

  k_logmap<<<64,256,0,stream>>>(xhyp, z0);
  k_gproj<<<96,256,0,stream>>>(projW, z0, gbuf);
  k_diff<<<512,256,0,stream>>>(kers, gbuf, hpart);
  k_hreduce<<<512,256,0,stream>>>(hpart, projb, h0);

  // layer 0
  k_qkv<true><<<96,256,0,stream>>>((const void*)h0, Wqkv, bqkv, qkvb);
  k_attn<<<512,256,0,stream>>>(qkvb, opart, mlprt);
  k_fused<true><<<32,256,0,stream>>>(opart, mlprt, Wo, bo, h0, g1, be1,
                                     W1, b1, W2, b2, g2, be2, x1f,
                                     Wqkv + (size_t)3*DIM*DIM, bqkv + 3*DIM, qkvb);
  // layer 1
  k_attn<<<512,256,0,stream>>>(qkvb, opart, mlprt);
  k_fused<false><<<32,256,0,stream>>>(opart, mlprt, Wo + (size_t)DIM*DIM, bo + DIM, x1f,
                                      g1 + DIM, be1 + DIM, W1 + (size_t)DIM*DIM, b1 + DIM,
                                      W2 + (size_t)DIM*DIM, b2 + DIM, g2 + DIM, be2 + DIM, x2f,
                                      nullptr, nullptr, nullptr);
  k_pool<<<4096,256,0,stream>>>(visits, x2f, (float*)d_out);
}

// Round 5
// 527.666 us; speedup vs baseline: 1.5045x; 1.4414x over previous
//
#include <hip/hip_runtime.h>
#include <hip/hip_bf16.h>
#include <math.h>

#define VN 4096
#define DIM 128
#define KS 3
#define NH 4
#define HD 32
#define NVIS 8192
#define MAXC 32
#define KTOT (KS*VN)   // 12288
#define PITCH 136      // LDS row pitch (bf16 elems) for small GEMMs

typedef unsigned short u16;
typedef __attribute__((ext_vector_type(8))) short short8;   // 8 bf16 (4 VGPRs)
typedef __attribute__((ext_vector_type(4))) float f32x4;
typedef __attribute__((ext_vector_type(4))) float f4v;      // for nontemporal loads

__device__ __forceinline__ u16 f2b(float f){
  union { float f; unsigned u; } c; c.f = f;
  unsigned u = c.u;
  return (u16)((u + 0x7fffu + ((u >> 16) & 1u)) >> 16);   // RTNE
}
__device__ __forceinline__ float b2f(u16 x){
  union { float f; unsigned u; } c; c.u = ((unsigned)x) << 16; return c.f;
}
// packed f32x2 -> bf16x2 (RTNE), dst.lo = lo, dst.hi = hi
__device__ __forceinline__ unsigned cvt2(float lo, float hi){
  unsigned r;
  asm("v_cvt_pk_bf16_f32 %0, %1, %2" : "=v"(r) : "v"(lo), "v"(hi));
  return r;
}
#define MFMA16(a,b,c) __builtin_amdgcn_mfma_f32_16x16x32_bf16((a),(b),(c),0,0,0)

// ---------------- weight pre-convert: all f32 weights -> bf16 workspace ----------------
// layout: wb[0..98303]=Wqkv(2 layers), +98304 Wo(2), +131072 W1(2), +163840 W2(2)
__global__ __launch_bounds__(256) void k_wprep(const float* __restrict__ Wqkv, const float* __restrict__ Wo,
                                               const float* __restrict__ W1, const float* __restrict__ W2,
                                               u16* __restrict__ wb){
  int t = blockIdx.x*256 + threadIdx.x;   // grid 96 -> 24576 threads, 2 groups of 4 each
  #pragma unroll
  for(int i=0;i<2;i++){
    int e = t + 24576*i;
    const float* s; u16* d; int ge;
    if(e < 24576){ s = Wqkv; d = wb;          ge = e; }
    else if(e < 32768){ s = Wo; d = wb + 98304;  ge = e - 24576; }
    else if(e < 40960){ s = W1; d = wb + 131072; ge = e - 32768; }
    else              { s = W2; d = wb + 163840; ge = e - 40960; }
    float4 f = *(const float4*)&s[(size_t)ge*4];
    uint2 o = { cvt2(f.x,f.y), cvt2(f.z,f.w) };
    *(uint2*)&d[(size_t)ge*4] = o;
  }
}

// ---------------- logmap0 (f32 in, bf16 out):  Z0 = artanh(||x||)/||x|| * x ----------------
__global__ __launch_bounds__(256) void k_logmap(const float* __restrict__ xh, u16* __restrict__ z0){
  __shared__ float xs[64][132];
  __shared__ float part[4][64];
  __shared__ float sscale[64];
  int t = threadIdx.x;
  int v0 = blockIdx.x * 64;
  #pragma unroll
  for(int i=0;i<8;i++){
    int id = t + 256*i; int e = id*4; int r = e>>7; int c = e&127;
    float4 u = *(const float4*)&xh[(size_t)(v0+r)*DIM + c];
    xs[r][c+0]=u.x; xs[r][c+1]=u.y; xs[r][c+2]=u.z; xs[r][c+3]=u.w;
  }
  __syncthreads();
  int r = t & 63, q = t >> 6;
  float p = 0.f;
  #pragma unroll
  for(int c=0;c<32;c++){ float x = xs[r][q*32+c]; p += x*x; }
  part[q][r] = p;
  __syncthreads();
  if(t < 64){
    float ss = part[0][t]+part[1][t]+part[2][t]+part[3][t];
    float n = sqrtf(ss);
    float nc = fminf(fmaxf(n, 1e-7f), 1.0f - 1e-5f);
    sscale[t] = atanhf(nc) / fmaxf(n, 1e-7f);
  }
  __syncthreads();
  #pragma unroll
  for(int i=0;i<8;i++){
    int id = t + 256*i; int e = id*4; int rr = e>>7; int cc = e&127;
    float s = sscale[rr];
    uint2 o = { cvt2(xs[rr][cc+0]*s, xs[rr][cc+1]*s),
                cvt2(xs[rr][cc+2]*s, xs[rr][cc+3]*s) };
    *(uint2*)&z0[(size_t)(v0+rr)*DIM + cc] = o;
  }
}

// ---------------- shared 128x128-tile GEMM core, K=128 (BK=64 x 2), pipelined --------------
// (used by k_gproj only now)
template<bool AF32, bool BF32>
__device__ __forceinline__ void gemm_k128_t(const void* __restrict__ Agv, int lda,
                                            const void* __restrict__ Bgv, int ldb,
                                            u16 (*As)[128*72], u16 (*Bs)[128*72], f32x4 (&acc)[2][8]){
  int t = threadIdx.x;
  int w=t>>6, lane=t&63, l15=lane&15, quad=lane>>4;
  #pragma unroll
  for(int s=0;s<2;s++)
    #pragma unroll
    for(int n=0;n<8;n++) acc[s][n] = (f32x4){0.f,0.f,0.f,0.f};

  float4 af[4][2]; uint4 ai[4];
  float4 bf[4][2]; uint4 bi[4];

  auto LOAD = [&](int kb){
    #pragma unroll
    for(int i=0;i<4;i++){
      int id = t + 256*i; int row = id>>3, c8 = id&7;
      if constexpr(AF32){
        const float* Ag = (const float*)Agv;
        af[i][0] = *(const float4*)&Ag[(size_t)row*lda + kb + c8*8];
        af[i][1] = *(const float4*)&Ag[(size_t)row*lda + kb + c8*8 + 4];
      } else {
        const u16* Ag = (const u16*)Agv;
        ai[i] = *(const uint4*)&Ag[(size_t)row*lda + kb + c8*8];
      }
      if constexpr(BF32){
        const float* Bg = (const float*)Bgv;
        bf[i][0] = *(const float4*)&Bg[(size_t)row*ldb + kb + c8*8];
        bf[i][1] = *(const float4*)&Bg[(size_t)row*ldb + kb + c8*8 + 4];
      } else {
        const u16* Bg = (const u16*)Bgv;
        bi[i] = *(const uint4*)&Bg[(size_t)row*ldb + kb + c8*8];
      }
    }
  };
  auto COMMIT = [&](u16* Ad, u16* Bd){
    #pragma unroll
    for(int i=0;i<4;i++){
      int id = t + 256*i; int row = id>>3, c8 = id&7;
      if constexpr(AF32){
        uint4 p = { cvt2(af[i][0].x, af[i][0].y), cvt2(af[i][0].z, af[i][0].w),
                    cvt2(af[i][1].x, af[i][1].y), cvt2(af[i][1].z, af[i][1].w) };
        *(uint4*)&Ad[row*72 + c8*8] = p;
      } else {
        *(uint4*)&Ad[row*72 + c8*8] = ai[i];
      }
      if constexpr(BF32){
        uint4 q = { cvt2(bf[i][0].x, bf[i][0].y), cvt2(bf[i][0].z, bf[i][0].w),
                    cvt2(bf[i][1].x, bf[i][1].y), cvt2(bf[i][1].z, bf[i][1].w) };
        *(uint4*)&Bd[row*72 + c8*8] = q;
      } else {
        *(uint4*)&Bd[row*72 + c8*8] = bi[i];
      }
    }
  };
  auto COMPUTE = [&](const u16* Asb, const u16* Bsb){
    #pragma unroll
    for(int ks=0; ks<2; ks++){
      short8 a[2], b[8];
      #pragma unroll
      for(int s=0;s<2;s++) a[s] = *(const short8*)&Asb[(w*32+s*16+l15)*72 + (ks*4+quad)*8];
      #pragma unroll
      for(int n=0;n<8;n++)  b[n] = *(const short8*)&Bsb[(n*16+l15)*72 + (ks*4+quad)*8];
      #pragma unroll
      for(int s=0;s<2;s++)
        #pragma unroll
        for(int n=0;n<8;n++) acc[s][n] = MFMA16(a[s], b[n], acc[s][n]);
    }
  };

  LOAD(0);  COMMIT(As[0], Bs[0]);  __syncthreads();
  LOAD(64); COMPUTE(As[0], Bs[0]); COMMIT(As[1], Bs[1]); __syncthreads();
  COMPUTE(As[1], Bs[1]);
}

// ---------------- G[d,k,v] = sum_d' projW[d,k*128+d'] Z0[v,d'], stored gbuf[d][k][v] ----------
__global__ __launch_bounds__(256) void k_gproj(const float* __restrict__ projW, const u16* __restrict__ z0,
                                               u16* __restrict__ gbuf){
  __shared__ u16 As[2][128*72], Bs[2][128*72];
  int kb = blockIdx.x >> 5, vt = blockIdx.x & 31;   // grid 96
  f32x4 acc[2][8];
  gemm_k128_t<true,false>(projW + kb*128, 3*DIM, z0 + (size_t)vt*128*DIM, DIM, As, Bs, acc);
  int t=threadIdx.x, w=t>>6, lane=t&63, l15=lane&15, quad=lane>>4;
  #pragma unroll
  for(int s=0;s<2;s++)
    #pragma unroll
    for(int n=0;n<8;n++)
      #pragma unroll
      for(int rg=0;rg<4;rg++){
        int d = w*32 + s*16 + quad*4 + rg;        // output row = (k,d) with k=kb
        int v = vt*128 + n*16 + l15;
        gbuf[(size_t)(d*KS + kb)*VN + v] = f2b(acc[s][n][rg]);
      }
}

// ---------------- diffusion GEMM: bf16 partial tiles, double-buffered & pipelined ------------
__global__ __launch_bounds__(256) void k_diff(const float* __restrict__ kers, const u16* __restrict__ gbuf,
                                              u16* __restrict__ hpart){
  __shared__ u16 As[2][128*72], Bs[2][128*72];
  int t = threadIdx.x;
  int mt = blockIdx.x & 31;     // M tile
  int sl = blockIdx.x >> 5;     // K slice 0..15 (768 each)
  int w=t>>6, lane=t&63, l15=lane&15, quad=lane>>4;
  f32x4 acc[2][8];
  #pragma unroll
  for(int s=0;s<2;s++)
    #pragma unroll
    for(int n=0;n<8;n++) acc[s][n] = (f32x4){0.f,0.f,0.f,0.f};
  int k0 = sl * 768;

  f4v  fa0[4], fa1[4];
  uint4 fb[4];

  auto LOADSTEP = [&](int step){
    int kk = k0 + step*64;
    int kout = kk >> 12; int vv = kk & 4095;      // 64-chunks never straddle the v=4096 boundary
    #pragma unroll
    for(int i=0;i<4;i++){
      int id = t + 256*i; int row = id>>3, c8 = id&7;
      const float* ap = &kers[((size_t)kout<<24) + (size_t)(mt*128+row)*VN + vv + c8*8];
      fa0[i] = __builtin_nontemporal_load((const f4v*)ap);       // streaming, no reuse
      fa1[i] = __builtin_nontemporal_load((const f4v*)(ap+4));
      fb[i]  = *(const uint4*)&gbuf[(size_t)row*KTOT + kk + c8*8];
    }
  };
  auto COMMIT = [&](u16* Ad, u16* Bd){
    #pragma unroll
    for(int i=0;i<4;i++){
      int id = t + 256*i; int row = id>>3, c8 = id&7;
      uint4 pa = { cvt2(fa0[i].x, fa0[i].y), cvt2(fa0[i].z, fa0[i].w),
                   cvt2(fa1[i].x, fa1[i].y), cvt2(fa1[i].z, fa1[i].w) };
      *(uint4*)&Ad[row*72 + c8*8] = pa;
      *(uint4*)&Bd[row*72 + c8*8] = fb[i];
    }
  };
  auto COMPUTE = [&](const u16* Asb, const u16* Bsb){
    #pragma unroll
    for(int ks=0; ks<2; ks++){
      short8 a[2], b[8];
      #pragma unroll
      for(int s=0;s<2;s++) a[s] = *(const short8*)&Asb[(w*32+s*16+l15)*72 + (ks*4+quad)*8];
      #pragma unroll
      for(int n=0;n<8;n++)  b[n] = *(const short8*)&Bsb[(n*16+l15)*72 + (ks*4+quad)*8];
      #pragma unroll
      for(int s=0;s<2;s++)
        #pragma unroll
        for(int n=0;n<8;n++) acc[s][n] = MFMA16(a[s], b[n], acc[s][n]);
    }
  };

  LOADSTEP(0);
  COMMIT(As[0], Bs[0]);
  __syncthreads();
  #pragma unroll 1
  for(int sp=0; sp<6; sp++){
    LOADSTEP(2*sp+1);
    COMPUTE(As[0], Bs[0]);
    COMMIT(As[1], Bs[1]);
    __syncthreads();
    if(sp < 5){
      LOADSTEP(2*sp+2);
      COMPUTE(As[1], Bs[1]);
      COMMIT(As[0], Bs[0]);
      __syncthreads();
    }
  }
  COMPUTE(As[1], Bs[1]);

  u16* dst = hpart + ((size_t)blockIdx.x << 14);   // 128x128 bf16 tile per block
  #pragma unroll
  for(int s=0;s<2;s++)
    #pragma unroll
    for(int n=0;n<8;n++)
      #pragma unroll
      for(int rg=0;rg<4;rg++)
        dst[(w*32+s*16+quad*4+rg)*128 + n*16 + l15] = f2b(acc[s][n][rg]);
}

// ---------------- reduce 16 bf16 partials + proj_b -> H0 f32 (vectorized uint2 loads) --------
__global__ __launch_bounds__(256) void k_hreduce(const u16* __restrict__ hpart, const float* __restrict__ pb,
                                                 float* __restrict__ h0){
  int idx = blockIdx.x*256 + threadIdx.x;   // grid 512 -> 131072 threads, 4 contiguous elems each
  int e0 = idx*4;
  int c0 = e0 & 127;
  float4 r;
  r.x = pb[c0+0]; r.y = pb[c0+1]; r.z = pb[c0+2]; r.w = pb[c0+3];
  #pragma unroll
  for(int sl=0; sl<16; sl++){
    uint2 u = *(const uint2*)&hpart[((size_t)sl<<19) + e0];
    r.x += b2f((u16)(u.x & 0xffffu)); r.y += b2f((u16)(u.x >> 16));
    r.z += b2f((u16)(u.y & 0xffffu)); r.w += b2f((u16)(u.y >> 16));
  }
  *(float4*)&h0[e0] = r;
}

// ======== small-GEMM toolkit: 32-row x 128-col tile, K=128 staged once, block=128 (2 waves) ===
__device__ __forceinline__ void sg_stageB(const u16* __restrict__ wb, u16* Bs){
  int t = threadIdx.x;
  #pragma unroll
  for(int i=0;i<16;i++){
    int e = t + 128*i; int row = e>>4, c16 = e&15;
    *(uint4*)&Bs[row*PITCH + c16*8] = *(const uint4*)&wb[row*128 + c16*8];
  }
}
__device__ __forceinline__ void sg_stageA_b(const u16* __restrict__ src, int m0, u16* As){
  int t = threadIdx.x;
  #pragma unroll
  for(int i=0;i<4;i++){
    int e = t + 128*i; int row = e>>4, c16 = e&15;
    *(uint4*)&As[row*PITCH + c16*8] = *(const uint4*)&src[(size_t)(m0+row)*DIM + c16*8];
  }
}
__device__ __forceinline__ void sg_stageA_f(const float* __restrict__ src, int m0, u16* As){
  int t = threadIdx.x;
  #pragma unroll
  for(int i=0;i<8;i++){
    int e = t + 128*i; int row = e>>5, c4 = e&31;
    float4 f = *(const float4*)&src[(size_t)(m0+row)*DIM + c4*4];
    uint2 o = { cvt2(f.x,f.y), cvt2(f.z,f.w) };
    *(uint2*)&As[row*PITCH + c4*4] = o;
  }
}
__device__ __forceinline__ void sg_compute(const u16* As, const u16* Bs, f32x4 (&acc)[8]){
  int t=threadIdx.x, w=t>>6, lane=t&63, l15=lane&15, quad=lane>>4;
  #pragma unroll
  for(int n=0;n<8;n++) acc[n] = (f32x4){0.f,0.f,0.f,0.f};
  #pragma unroll
  for(int kk=0;kk<4;kk++){
    short8 a = *(const short8*)&As[(w*16+l15)*PITCH + kk*32 + quad*8];
    #pragma unroll
    for(int n=0;n<8;n++){
      short8 b = *(const short8*)&Bs[(n*16+l15)*PITCH + kk*32 + quad*8];
      acc[n] = MFMA16(a, b, acc[n]);
    }
  }
}
__device__ __forceinline__ void sg_ln(f32x4 (&acc)[8], const float* __restrict__ g,
                                      const float* __restrict__ bv, int l15){
  #pragma unroll
  for(int rg=0;rg<4;rg++){
    float a=0.f, bs=0.f;
    #pragma unroll
    for(int n=0;n<8;n++){ float x = acc[n][rg]; a += x; bs += x*x; }
    #pragma unroll
    for(int off=1;off<16;off<<=1){ a += __shfl_xor(a, off, 64); bs += __shfl_xor(bs, off, 64); }
    float mean = a*(1.f/128.f);
    float var  = bs*(1.f/128.f) - mean*mean;
    float rstd = rsqrtf(var + 1e-5f);
    #pragma unroll
    for(int n=0;n<8;n++){
      int col = n*16 + l15;
      acc[n][rg] = (acc[n][rg] - mean)*rstd*g[col] + bv[col];
    }
  }
}

// ---------------- qkv = x @ Wqkv^T + b (bf16 out); grid 384 = 128 M-tiles x 3 N-tiles --------
template<bool AF32>
__global__ __launch_bounds__(128) void k_qkv_s(const void* __restrict__ xb, const u16* __restrict__ wq,
                                               const float* __restrict__ bq, u16* __restrict__ outq){
  __shared__ u16 As[32*PITCH], Bs[128*PITCH];
  int bx = blockIdx.x; int mt = bx & 127, nt = bx >> 7;
  if(AF32) sg_stageA_f((const float*)xb, mt*32, As);
  else     sg_stageA_b((const u16*)xb, mt*32, As);
  sg_stageB(wq + nt*16384, Bs);
  __syncthreads();
  f32x4 acc[8]; sg_compute(As, Bs, acc);
  int t=threadIdx.x, w=t>>6, lane=t&63, l15=lane&15, quad=lane>>4;
  #pragma unroll
  for(int n=0;n<8;n++)
    #pragma unroll
    for(int rg=0;rg<4;rg++){
      int row = mt*32 + w*16 + quad*4 + rg;
      int col = nt*128 + n*16 + l15;
      outq[(size_t)row*(3*DIM) + col] = f2b(acc[n][rg] + bq[col]);
    }
}

// ---------------- attn-out proj + bias + residual + LN1; grid 128 ----------------
__global__ __launch_bounds__(128) void k_oprojln_s(const float* __restrict__ opart, const float* __restrict__ mlpart,
                                                   const u16* __restrict__ wo,
                                                   const float* __restrict__ bias, const float* __restrict__ resf,
                                                   const float* __restrict__ g, const float* __restrict__ bb,
                                                   float* __restrict__ outf, u16* __restrict__ outb){
  __shared__ u16 As[32*PITCH], Bs[128*PITCH];
  int mt = blockIdx.x; int t = threadIdx.x;
  #pragma unroll
  for(int i=0;i<8;i++){                    // A: combined attention output -> bf16
    int e = t + 128*i; int row = e>>5, c4 = e&31; int col = c4*4;
    int hh = col>>5, c0 = col&31;
    int grow = mt*32 + row;
    int hq = hh*64 + (grow>>6); int rr = grow & 63;
    const float* o0  = opart  + ((size_t)(hq*2)   << 11);
    const float* o1  = opart  + ((size_t)(hq*2+1) << 11);
    const float* ml0 = mlpart + ((size_t)(hq*2)   << 7);
    const float* ml1 = mlpart + ((size_t)(hq*2+1) << 7);
    float m0 = ml0[rr], l0 = ml0[64+rr], m1 = ml1[rr], l1 = ml1[64+rr];
    float m = fmaxf(m0, m1);
    float w0 = __expf(m0 - m), w1 = __expf(m1 - m);
    float inv = 1.f / (l0*w0 + l1*w1);
    float4 a  = *(const float4*)&o0[rr*32 + c0];
    float4 c  = *(const float4*)&o1[rr*32 + c0];
    uint2 o = { cvt2((a.x*w0+c.x*w1)*inv, (a.y*w0+c.y*w1)*inv),
                cvt2((a.z*w0+c.z*w1)*inv, (a.w*w0+c.w*w1)*inv) };
    *(uint2*)&As[row*PITCH + col] = o;
  }
  sg_stageB(wo, Bs);
  __syncthreads();
  f32x4 acc[8]; sg_compute(As, Bs, acc);
  int w=t>>6, lane=t&63, l15=lane&15, quad=lane>>4;
  #pragma unroll
  for(int n=0;n<8;n++)
    #pragma unroll
    for(int rg=0;rg<4;rg++){
      int row = mt*32 + w*16 + quad*4 + rg;
      int col = n*16 + l15;
      acc[n][rg] += bias[col] + resf[(size_t)row*DIM + col];
    }
  sg_ln(acc, g, bb, l15);
  #pragma unroll
  for(int n=0;n<8;n++)
    #pragma unroll
    for(int rg=0;rg<4;rg++){
      int row = mt*32 + w*16 + quad*4 + rg;
      int col = n*16 + l15;
      float y = acc[n][rg];
      outf[(size_t)row*DIM + col] = y;
      outb[(size_t)row*DIM + col] = f2b(y);
    }
}

// ---------------- ff1 = gelu_tanh(x @ W1^T + b1) -> bf16; grid 128 ----------------
__global__ __launch_bounds__(128) void k_ff1_s(const u16* __restrict__ Ab, const u16* __restrict__ w1,
                                               const float* __restrict__ bias, u16* __restrict__ outb){
  __shared__ u16 As[32*PITCH], Bs[128*PITCH];
  int mt = blockIdx.x;
  sg_stageA_b(Ab, mt*32, As);
  sg_stageB(w1, Bs);
  __syncthreads();
  f32x4 acc[8]; sg_compute(As, Bs, acc);
  int t=threadIdx.x, w=t>>6, lane=t&63, l15=lane&15, quad=lane>>4;
  #pragma unroll
  for(int n=0;n<8;n++)
    #pragma unroll
    for(int rg=0;rg<4;rg++){
      int row = mt*32 + w*16 + quad*4 + rg;
      int col = n*16 + l15;
      float v = acc[n][rg] + bias[col];
      float z = 0.7978845608028654f*(v + 0.044715f*v*v*v);
      float e = __expf(2.f*z);
      float th = 1.f - 2.f/(e + 1.f);     // tanh(z), overflow-safe
      outb[(size_t)row*DIM + col] = f2b(0.5f*v*(1.f + th));
    }
}

// ---------------- C = A@W2^T + b2 + residual, LN2 -> f32 + bf16; grid 128 ----------------
__global__ __launch_bounds__(128) void k_projln_s(const u16* __restrict__ Ab, const u16* __restrict__ w2,
                                                  const float* __restrict__ bias, const float* __restrict__ resf,
                                                  const float* __restrict__ g, const float* __restrict__ bb,
                                                  float* __restrict__ outf, u16* __restrict__ outb){
  __shared__ u16 As[32*PITCH], Bs[128*PITCH];
  int mt = blockIdx.x;
  sg_stageA_b(Ab, mt*32, As);
  sg_stageB(w2, Bs);
  __syncthreads();
  f32x4 acc[8]; sg_compute(As, Bs, acc);
  int t=threadIdx.x, w=t>>6, lane=t&63, l15=lane&15, quad=lane>>4;
  #pragma unroll
  for(int n=0;n<8;n++)
    #pragma unroll
    for(int rg=0;rg<4;rg++){
      int row = mt*32 + w*16 + quad*4 + rg;
      int col = n*16 + l15;
      acc[n][rg] += bias[col] + resf[(size_t)row*DIM + col];
    }
  sg_ln(acc, g, bb, l15);
  #pragma unroll
  for(int n=0;n<8;n++)
    #pragma unroll
    for(int rg=0;rg<4;rg++){
      int row = mt*32 + w*16 + quad*4 + rg;
      int col = n*16 + l15;
      float y = acc[n][rg];
      outf[(size_t)row*DIM + col] = y;
      outb[(size_t)row*DIM + col] = f2b(y);
    }
}

// ---------------- flash attention, kt-split x2, software-pipelined K/V ----------------
// 1 barrier/iter; exact skip-rescale (alpha==1 fast path) when tile max doesn't grow.
__global__ __launch_bounds__(256) void k_attn(const u16* __restrict__ qkv, float* __restrict__ opart,
                                              float* __restrict__ mlpart){
  __shared__ u16 Qs[64*40];
  __shared__ u16 Ksh[2][128*40];
  __shared__ u16 Vt[2][32*136];
  __shared__ u16 Ps[4*16*136];
  int t=threadIdx.x;
  int b = blockIdx.x;                       // grid 512
  int h = b>>7, qt = (b>>1)&63, half = b&1;
  int w=t>>6, lane=t&63, l15=lane&15, quad=lane>>4;
  { int r = t>>2, c = t&3;
    *(uint4*)&Qs[r*40 + c*8] = *(const uint4*)&qkv[(size_t)(qt*64+r)*(3*DIM) + h*HD + c*8];
  }
  int skey = t>>2, sc4 = t&3;               // staging coords (2 iters: skey, skey+64)
  uint4 kreg[2], vreg[2];
  #pragma unroll
  for(int i=0;i<2;i++){
    int key = skey + 64*i;
    kreg[i] = *(const uint4*)&qkv[(size_t)((size_t)(half*16)*128+key)*(3*DIM) + DIM + h*HD + sc4*8];
    vreg[i] = *(const uint4*)&qkv[(size_t)((size_t)(half*16)*128+key)*(3*DIM) + 2*DIM + h*HD + sc4*8];
  }
  #pragma unroll
  for(int i=0;i<2;i++){
    int key = skey + 64*i;
    *(uint4*)&Ksh[0][key*40 + sc4*8] = kreg[i];
    u16 tmp[8]; *(uint4*)tmp = vreg[i];
    #pragma unroll
    for(int j=0;j<8;j++) Vt[0][(sc4*8+j)*136 + key] = tmp[j];
  }
  __syncthreads();
  short8 aq = *(short8*)&Qs[(w*16+l15)*40 + quad*8];
  f32x4 oacc[2]; oacc[0]=(f32x4){0.f,0.f,0.f,0.f}; oacc[1]=(f32x4){0.f,0.f,0.f,0.f};
  float mrun[4], lrun[4];
  #pragma unroll
  for(int rg=0;rg<4;rg++){ mrun[rg] = -INFINITY; lrun[rg] = 0.f; }
  const float sc = 0.17677669529663687f;  // 1/sqrt(32)
  for(int kti=0;kti<16;kti++){
    int cur = kti&1;
    if(kti<15){                             // issue next K/V global loads (no wait yet)
      int kt = half*16 + kti + 1;
      #pragma unroll
      for(int i=0;i<2;i++){
        int key = skey + 64*i;
        kreg[i] = *(const uint4*)&qkv[(size_t)(kt*128+key)*(3*DIM) + DIM + h*HD + sc4*8];
        vreg[i] = *(const uint4*)&qkv[(size_t)(kt*128+key)*(3*DIM) + 2*DIM + h*HD + sc4*8];
      }
    }
    f32x4 s[8];
    #pragma unroll
    for(int n=0;n<8;n++)
      s[n] = MFMA16(aq, *(short8*)&Ksh[cur][(n*16+l15)*40 + quad*8], ((f32x4){0.f,0.f,0.f,0.f}));
    float mx[4];
    #pragma unroll
    for(int rg=0;rg<4;rg++){
      float m = -INFINITY;
      #pragma unroll
      for(int n=0;n<8;n++) m = fmaxf(m, s[n][rg]);
      #pragma unroll
      for(int off=1;off<16;off<<=1) m = fmaxf(m, __shfl_xor(m, off, 64));
      mx[rg] = m;
    }
    // exact skip-rescale: if no row's max grew, alpha == 1 for every row -> skip the work
    bool grew = false;
    #pragma unroll
    for(int rg=0;rg<4;rg++) grew = grew || (mx[rg] > mrun[rg]);
    if(__any(grew)){
      #pragma unroll
      for(int rg=0;rg<4;rg++){
        float mn = fmaxf(mrun[rg], mx[rg]);
        float alpha = __expf(sc*(mrun[rg] - mn));   // raw-domain m, scale folded into exp
        mrun[rg] = mn;
        lrun[rg] *= alpha;
        oacc[0][rg] *= alpha; oacc[1][rg] *= alpha;
      }
    }
    float rs[4];
    #pragma unroll
    for(int rg=0;rg<4;rg++) rs[rg] = 0.f;
    #pragma unroll
    for(int n=0;n<8;n++)
      #pragma unroll
      for(int rg=0;rg<4;rg++){
        float p = __expf(sc*(s[n][rg] - mrun[rg]));
        s[n][rg] = p; rs[rg] += p;
      }
    #pragma unroll
    for(int rg=0;rg<4;rg++){
      #pragma unroll
      for(int off=1;off<16;off<<=1) rs[rg] += __shfl_xor(rs[rg], off, 64);
      lrun[rg] += rs[rg];
    }
    // P: C-layout -> LDS -> A-layout; own-wave region only, lgkmcnt wait suffices (no barrier)
    #pragma unroll
    for(int n=0;n<8;n++)
      #pragma unroll
      for(int rg=0;rg<4;rg++)
        Ps[w*16*136 + (quad*4+rg)*136 + n*16 + l15] = f2b(s[n][rg]);
    #pragma unroll
    for(int kt2=0;kt2<4;kt2++){
      short8 ap = *(short8*)&Ps[w*16*136 + l15*136 + kt2*32 + quad*8];
      #pragma unroll
      for(int n2=0;n2<2;n2++)
        oacc[n2] = MFMA16(ap, *(short8*)&Vt[cur][(n2*16+l15)*136 + kt2*32 + quad*8], oacc[n2]);
    }
    if(kti<15){                             // commit next K/V to the other LDS buffer
      #pragma unroll
      for(int i=0;i<2;i++){
        int key = skey + 64*i;
        *(uint4*)&Ksh[cur^1][key*40 + sc4*8] = kreg[i];
        u16 tmp[8]; *(uint4*)tmp = vreg[i];
        #pragma unroll
        for(int j=0;j<8;j++) Vt[cur^1][(sc4*8+j)*136 + key] = tmp[j];
      }
    }
    __syncthreads();
  }
  float* op = opart + ((size_t)b << 11);          // 64 x 32 f32
  #pragma unroll
  for(int n2=0;n2<2;n2++)
    #pragma unroll
    for(int rg=0;rg<4;rg++)
      op[(w*16+quad*4+rg)*32 + n2*16 + l15] = oacc[n2][rg];
  if(l15 == 0){
    float* ml = mlpart + ((size_t)b << 7);        // [2][64]
    #pragma unroll
    for(int rg=0;rg<4;rg++){
      int r = w*16 + quad*4 + rg;
      ml[r] = sc*mrun[rg]; ml[64 + r] = lrun[rg]; // store m in scaled domain
    }
  }
}

// ---------------- per-visit masked mean pooling (f32 out) ----------------
__global__ __launch_bounds__(256) void k_pool(const int* __restrict__ visits, const float* __restrict__ xf,
                                              float* __restrict__ out){
  int t = threadIdx.x;
  int vis = blockIdx.x*2 + (t>>7);
  int col = t & 127;
  float s = 0.f; int cnt = 0;
  #pragma unroll
  for(int j=0;j<MAXC;j++){
    int idx = visits[vis*MAXC + j];
    if(idx != 0){ s += xf[(size_t)idx*DIM + col]; cnt++; }
  }
  float r = (cnt > 0) ? s/(float)cnt : 0.f;
  out[(size_t)vis*DIM + col] = r;
}

extern "C" void kernel_launch(void* const* d_in, const int* in_sizes, int n_in,
                              void* d_out, int out_size, void* d_ws, size_t ws_size,
                              hipStream_t stream){
  (void)in_sizes; (void)n_in; (void)out_size; (void)ws_size;
  const int*   visits = (const int*)d_in[0];
  const float* xhyp  = (const float*)d_in[1];
  const float* kers  = (const float*)d_in[2];
  const float* projW = (const float*)d_in[3];
  const float* projb = (const float*)d_in[4];
  const float* Wqkv  = (const float*)d_in[5];
  const float* bqkv  = (const float*)d_in[6];
  const float* Wo    = (const float*)d_in[7];
  const float* bo    = (const float*)d_in[8];
  const float* W1    = (const float*)d_in[9];
  const float* b1    = (const float*)d_in[10];
  const float* W2    = (const float*)d_in[11];
  const float* b2    = (const float*)d_in[12];
  const float* g1    = (const float*)d_in[13];
  const float* be1   = (const float*)d_in[14];
  const float* g2    = (const float*)d_in[15];
  const float* be2   = (const float*)d_in[16];

  char* ws = (char*)d_ws;
  u16*   z0    = (u16*)(ws);                // 1 MB : Z0 bf16 [4096][128]
  u16*   gbuf  = (u16*)(ws + (1u<<20));     // 3 MB : G bf16 [128][3][4096]
  float* h0    = (float*)(ws + (4u<<20));   // 2 MB : H0 f32
  u16*   qkvb  = (u16*)(ws + (7u<<20));     // 3 MB
  float* ln1f  = (float*)(ws + (11u<<20));  // 2 MB
  u16*   ln1b  = (u16*)(ws + (13u<<20));    // 1 MB
  u16*   ffa   = (u16*)(ws + (14u<<20));    // 1 MB
  float* x1f   = (float*)(ws + (15u<<20));  // 2 MB
  u16*   x1b   = (u16*)(ws + (17u<<20));    // 1 MB
  float* x2f   = (float*)(ws + (18u<<20));  // 2 MB
  u16*   x2b   = (u16*)(ws + (20u<<20));    // 1 MB
  u16*   hpart = (u16*)(ws + (21u<<20));    // 16 MB : 512 x (128x128) bf16 partials
  u16*   wb    = (u16*)(ws + (40u<<20));    // 384 KB: bf16 weights
  float* opart = (float*)(ws + (53u<<20));  // 4 MB  : 512 x (64x32) f32
  float* mlprt = (float*)(ws + (57u<<20));  // 256 KB: 512 x [2][64] f32

  k_wprep<<<96,256,0,stream>>>(Wqkv, Wo, W1, W2, wb);
  k_logmap<<<64,256,0,stream>>>(xhyp, z0);
  k_gproj<<<96,256,0,stream>>>(projW, z0, gbuf);
  k_diff<<<512,256,0,stream>>>(kers, gbuf, hpart);
  k_hreduce<<<512,256,0,stream>>>(hpart, projb, h0);

  const u16* wq_l[2] = { wb,            wb + 49152 };
  const u16* wo_l[2] = { wb + 98304,    wb + 98304 + 16384 };
  const u16* w1_l[2] = { wb + 131072,   wb + 131072 + 16384 };
  const u16* w2_l[2] = { wb + 163840,   wb + 163840 + 16384 };

  // layer 0
  k_qkv_s<true><<<384,128,0,stream>>>((const void*)h0, wq_l[0], bqkv, qkvb);
  k_attn<<<512,256,0,stream>>>(qkvb, opart, mlprt);
  k_oprojln_s<<<128,128,0,stream>>>(opart, mlprt, wo_l[0], bo, h0, g1, be1, ln1f, ln1b);
  k_ff1_s<<<128,128,0,stream>>>(ln1b, w1_l[0], b1, ffa);
  k_projln_s<<<128,128,0,stream>>>(ffa, w2_l[0], b2, ln1f, g2, be2, x1f, x1b);
  // layer 1
  k_qkv_s<false><<<384,128,0,stream>>>((const void*)x1b, wq_l[1], bqkv + 3*DIM, qkvb);
  k_attn<<<512,256,0,stream>>>(qkvb, opart, mlprt);
  k_oprojln_s<<<128,128,0,stream>>>(opart, mlprt, wo_l[1], bo + DIM, x1f, g1 + DIM, be1 + DIM, ln1f, ln1b);
  k_ff1_s<<<128,128,0,stream>>>(ln1b, w1_l[1], b1 + DIM, ffa);
  k_projln_s<<<128,128,0,stream>>>(ffa, w2_l[1], b2 + DIM, ln1f, g2 + DIM, be2 + DIM, x2f, x2b);

  k_pool<<<4096,256,0,stream>>>(visits, x2f, (float*)d_out);
}